// Round 6
// baseline (377.647 us; speedup 1.0000x reference)
//
#include <hip/hip_runtime.h>
#include <cstddef>

#define DD 128
#define BN_EPS 1e-5f
#define SLOPE 0.01f
#define BSH 6              // 64 dst rows per bucket
#define BROWS 64
#define CPAD 16            // cursor padding (ints) -> one cacheline per cursor
#define CAP 4096           // aggb per-chunk edge capacity in LDS
#define SCHUNK 4096        // scatb per-block edge chunk
#define CSH 13             // src-chunk shift: 8192 rows = 2 MB bf16, L2-resident
#define NCH 7              // ceil(50000/8192)

__device__ __forceinline__ float b2f(unsigned short u) {
    return __uint_as_float(((unsigned)u) << 16);
}
__device__ __forceinline__ unsigned short f2b(float x) {
    unsigned b = __float_as_uint(x);
    b += 0x7fffu + ((b >> 16) & 1u);   // round-to-nearest-even
    return (unsigned short)(b >> 16);
}
__device__ __forceinline__ void acc4(float4& a, uint2 u) {
    a.x += __uint_as_float(u.x << 16);
    a.y += __uint_as_float(u.x & 0xffff0000u);
    a.z += __uint_as_float(u.y << 16);
    a.w += __uint_as_float(u.y & 0xffff0000u);
}

// ---------- h (fp32) -> hb (bf16), RNE ----------
__global__ __launch_bounds__(256) void h2b_kernel(const float* __restrict__ h,
                                                  ushort* __restrict__ hb, int total4) {
    int i = blockIdx.x * blockDim.x + threadIdx.x;
    if (i >= total4) return;
    float4 v = ((const float4*)h)[i];
    ushort4 o;
    o.x = f2b(v.x); o.y = f2b(v.y); o.z = f2b(v.z); o.w = f2b(v.w);
    ((ushort4*)hb)[i] = o;
}

// ---------- bucket histogram ----------
__global__ __launch_bounds__(256) void histb_kernel(const int* __restrict__ dst,
                                                    int* __restrict__ bcnt,
                                                    int E, int NB) {
    __shared__ int bins[1024];
    for (int i = threadIdx.x; i < NB; i += blockDim.x) bins[i] = 0;
    __syncthreads();
    for (int e = blockIdx.x * blockDim.x + threadIdx.x; e < E;
         e += gridDim.x * blockDim.x)
        atomicAdd(&bins[dst[e] >> BSH], 1);
    __syncthreads();
    for (int i = threadIdx.x; i < NB; i += blockDim.x)
        if (bins[i]) atomicAdd(&bcnt[i], bins[i]);
}

// ---------- exclusive scan of bucket counts (NB <= 1024) ----------
__global__ __launch_bounds__(1024) void scanb_kernel(const int* __restrict__ bcnt,
                                                     int* __restrict__ off,
                                                     int* __restrict__ cursor, int NB) {
    __shared__ int s[1024];
    const int t = threadIdx.x;
    int v = (t < NB) ? bcnt[t] : 0;
    s[t] = v;
    __syncthreads();
    for (int d = 1; d < 1024; d <<= 1) {
        int u = (t >= d) ? s[t - d] : 0;
        __syncthreads();
        s[t] += u;
        __syncthreads();
    }
    if (t < NB) {
        int excl = s[t] - v;
        off[t] = excl;
        cursor[t * CPAD] = excl;
    }
    if (t == 0) off[NB] = s[1023];
}

// ---------- sorted chunk scatter ----------
__global__ __launch_bounds__(256) void scatb2_kernel(const int* __restrict__ src,
                                                     const int* __restrict__ dst,
                                                     int* __restrict__ cursor,
                                                     unsigned* __restrict__ packed,
                                                     int E, int NB) {
    __shared__ int bins[1024];
    __shared__ int lofs[1024];
    __shared__ int lcur[1024];
    __shared__ int gbase[1024];
    __shared__ unsigned sbuf[SCHUNK];
    __shared__ int wtot[4];

    const int t = threadIdx.x;
    const int lane = t & 63;
    const int w = t >> 6;
    const int cs = blockIdx.x * SCHUNK;
    const int cn = min(SCHUNK, E - cs);

#pragma unroll
    for (int k = 0; k < 4; ++k) bins[t + 256 * k] = 0;
    __syncthreads();
    for (int i = t; i < cn; i += 256) atomicAdd(&bins[dst[cs + i] >> BSH], 1);
    __syncthreads();

    const int b0 = 4 * t;
    int c0 = bins[b0], c1 = bins[b0 + 1], c2 = bins[b0 + 2], c3 = bins[b0 + 3];
    int s = c0 + c1 + c2 + c3;
    int si = s;
#pragma unroll
    for (int d = 1; d < 64; d <<= 1) {
        int u = __shfl_up(si, d);
        if (lane >= d) si += u;
    }
    if (lane == 63) wtot[w] = si;
    __syncthreads();
    if (t == 0) {
        int a = 0;
#pragma unroll
        for (int k = 0; k < 4; ++k) { int v = wtot[k]; wtot[k] = a; a += v; }
    }
    __syncthreads();
    int excl = wtot[w] + si - s;
    lofs[b0] = excl; lcur[b0] = excl;
    lofs[b0 + 1] = excl + c0; lcur[b0 + 1] = excl + c0;
    lofs[b0 + 2] = excl + c0 + c1; lcur[b0 + 2] = excl + c0 + c1;
    lofs[b0 + 3] = excl + c0 + c1 + c2; lcur[b0 + 3] = excl + c0 + c1 + c2;
    __syncthreads();

    for (int b = t; b < NB; b += 256) {
        int c = bins[b];
        if (c) gbase[b] = atomicAdd(&cursor[b * CPAD], c) - lofs[b];
    }
    for (int i = t; i < cn; i += 256) {
        int d = dst[cs + i];
        int b = d >> BSH;
        int pos = atomicAdd(&lcur[b], 1);
        sbuf[pos] = ((unsigned)b << 22) | ((unsigned)(d & (BROWS - 1)) << 16)
                    | (unsigned)src[cs + i];
    }
    __syncthreads();
    for (int i = t; i < cn; i += 256) {
        unsigned p = sbuf[i];
        int b = (int)(p >> 22);
        packed[gbase[b] + i] = p;
    }
}

// ---------- split fused counting-sort + wide register gather ----------
// Grid = NB*2: sub-block s handles half of bucket b's edges, writes its
// partial to p0 (s=0) or p1 (s=1, aliased onto d_out). Lanes 0..31 cover the
// full 128-dim row as uint2 (8B); half-waves process alternate edges (512 B
// per wave-load-instr); cross-half-wave combine via shfl at the end.
__global__ __launch_bounds__(256) void aggb3_kernel(const ushort* __restrict__ hb,
                                                    const int* __restrict__ off,
                                                    const unsigned* __restrict__ packed,
                                                    float* __restrict__ p0,
                                                    float* __restrict__ p1, int n) {
    __shared__ int bins[512];
    __shared__ int cofs[513];
    __shared__ int ccur[512];
    __shared__ unsigned short sbuf[CAP];
    __shared__ int wtot[4];

    const int t = threadIdx.x;
    const int lane = t & 63;
    const int cg = lane & 31;        // column group: elems 4cg..4cg+3
    const int hw = lane >> 5;        // half-wave id
    const int w = t >> 6;
    const int b = blockIdx.x >> 1;
    const int sb = blockIdx.x & 1;
    float* part = sb ? p1 : p0;

    const int e0f = off[b];
    const int e1f = off[b + 1];
    const int len = e1f - e0f;
    const int half = (len + 1) >> 1;
    const int e0 = e0f + sb * half;
    const int e1 = min(e0f + half * (sb + 1), e1f);

    float4 acc[16];
#pragma unroll
    for (int i = 0; i < 16; ++i) acc[i] = make_float4(0.f, 0.f, 0.f, 0.f);

    for (int cs = e0; cs < e1; cs += CAP) {
        const int cn = min(CAP, e1 - cs);
        bins[t] = 0; bins[t + 256] = 0;
        __syncthreads();
        for (int i = t; i < cn; i += 256) {
            unsigned p = packed[cs + i];
            int key = (int)((((p & 0xffffu) >> CSH) << 6) | ((p >> 16) & 63u));
            atomicAdd(&bins[key], 1);
        }
        __syncthreads();
        int c0 = bins[2 * t], c1 = bins[2 * t + 1];
        int s = c0 + c1;
        int si = s;
#pragma unroll
        for (int d = 1; d < 64; d <<= 1) {
            int u = __shfl_up(si, d);
            if (lane >= d) si += u;
        }
        if (lane == 63) wtot[w] = si;
        __syncthreads();
        if (t == 0) {
            int a = 0;
#pragma unroll
            for (int k = 0; k < 4; ++k) { int v = wtot[k]; wtot[k] = a; a += v; }
        }
        __syncthreads();
        int excl = wtot[w] + si - s;
        cofs[2 * t] = excl;          ccur[2 * t] = excl;
        cofs[2 * t + 1] = excl + c0; ccur[2 * t + 1] = excl + c0;
        if (t == 255) cofs[512] = excl + c0 + c1;
        __syncthreads();
        for (int i = t; i < cn; i += 256) {
            unsigned p = packed[cs + i];
            int key = (int)((((p & 0xffffu) >> CSH) << 6) | ((p >> 16) & 63u));
            int pos = atomicAdd(&ccur[key], 1);
            sbuf[pos] = (unsigned short)(p & 0xffffu);
        }
        __syncthreads();

        for (int c = 0; c < NCH; ++c) {
            const int kbase = c * 64 + w * 16;
#pragma unroll
            for (int i = 0; i < 16; ++i) {
                const int jb = cofs[kbase + i];
                const int je = cofs[kbase + i + 1];
                float4 a = acc[i];
                int j = jb;
                for (; j + 8 <= je; j += 8) {
                    int s0 = sbuf[j + 0 + hw];
                    int s1 = sbuf[j + 2 + hw];
                    int s2 = sbuf[j + 4 + hw];
                    int s3 = sbuf[j + 6 + hw];
                    uint2 u0 = ((const uint2*)(hb + (size_t)s0 * DD))[cg];
                    uint2 u1 = ((const uint2*)(hb + (size_t)s1 * DD))[cg];
                    uint2 u2 = ((const uint2*)(hb + (size_t)s2 * DD))[cg];
                    uint2 u3 = ((const uint2*)(hb + (size_t)s3 * DD))[cg];
                    acc4(a, u0); acc4(a, u1); acc4(a, u2); acc4(a, u3);
                }
                for (; j + 2 <= je; j += 2) {
                    int s0 = sbuf[j + hw];
                    uint2 u0 = ((const uint2*)(hb + (size_t)s0 * DD))[cg];
                    acc4(a, u0);
                }
                if (j < je && hw == 0) {
                    int s0 = sbuf[j];
                    uint2 u0 = ((const uint2*)(hb + (size_t)s0 * DD))[cg];
                    acc4(a, u0);
                }
                acc[i] = a;
            }
        }
        __syncthreads();
    }

    const int r0 = b << BSH;
#pragma unroll
    for (int i = 0; i < 16; ++i) {
        float4 a = acc[i];
        a.x += __shfl_down(a.x, 32);
        a.y += __shfl_down(a.y, 32);
        a.z += __shfl_down(a.z, 32);
        a.w += __shfl_down(a.w, 32);
        int u = r0 + w * 16 + i;
        if (hw == 0 && u < n)
            ((float4*)(part + (size_t)u * DD))[cg] = a;
    }
}

// ---------------- GEMM: out[n,128] = act(A[n,128] @ W[128,128] + bias) ----
// FUSE_IN: A = epsval*A0 + A1 + A2 (two aggregation partials)
template <bool FUSE_IN, bool RELU, bool STATS>
__global__ __launch_bounds__(256) void gemm_kernel(
        const float* __restrict__ A0, const float* __restrict__ A1,
        const float* __restrict__ A2, const float* __restrict__ eps_ptr,
        const float* __restrict__ W, const float* __restrict__ bias,
        float* __restrict__ out, float* __restrict__ stats, int n) {
    __shared__ float As[64][36];
    __shared__ float Ws[32][128];
    __shared__ float Ssum[128];
    __shared__ float Ssq[128];

    const int t = threadIdx.x;
    const int cg = t & 31;
    const int rg = t >> 5;
    const int row0 = blockIdx.x * 64;

    float epsval = 1.0f;
    if (FUSE_IN) epsval = 1.0f + *eps_ptr;

    if (STATS) {
        if (t < 128) { Ssum[t] = 0.0f; Ssq[t] = 0.0f; }
    }

    float acc[8][4];
#pragma unroll
    for (int i = 0; i < 8; ++i)
#pragma unroll
        for (int j = 0; j < 4; ++j) acc[i][j] = 0.0f;

    for (int k0 = 0; k0 < 128; k0 += 32) {
#pragma unroll
        for (int jj = 0; jj < 2; ++jj) {
            int j = t + jj * 256;
            int r = j >> 3;
            int c4 = j & 7;
            int row = row0 + r;
            float4 v = make_float4(0.f, 0.f, 0.f, 0.f);
            if (row < n) {
                v = *((const float4*)(A0 + (size_t)row * DD + k0) + c4);
                if (FUSE_IN) {
                    float4 u = *((const float4*)(A1 + (size_t)row * DD + k0) + c4);
                    float4 u2 = *((const float4*)(A2 + (size_t)row * DD + k0) + c4);
                    v.x = epsval * v.x + u.x + u2.x;
                    v.y = epsval * v.y + u.y + u2.y;
                    v.z = epsval * v.z + u.z + u2.z;
                    v.w = epsval * v.w + u.w + u2.w;
                }
            }
            *(float4*)&As[r][c4 * 4] = v;
        }
#pragma unroll
        for (int jj = 0; jj < 4; ++jj) {
            int j = t + jj * 256;
            int r = j >> 5;
            int c4 = j & 31;
            *(float4*)&Ws[r][c4 * 4] = *((const float4*)(W + (size_t)(k0 + r) * DD) + c4);
        }
        __syncthreads();
#pragma unroll
        for (int kk = 0; kk < 32; ++kk) {
            float4 w = *(float4*)&Ws[kk][cg * 4];
#pragma unroll
            for (int i = 0; i < 8; ++i) {
                float a = As[rg * 8 + i][kk];
                acc[i][0] = fmaf(a, w.x, acc[i][0]);
                acc[i][1] = fmaf(a, w.y, acc[i][1]);
                acc[i][2] = fmaf(a, w.z, acc[i][2]);
                acc[i][3] = fmaf(a, w.w, acc[i][3]);
            }
        }
        __syncthreads();
    }

    const float4 bv = *((const float4*)bias + cg);
    float psum[4] = {0.f, 0.f, 0.f, 0.f};
    float psq[4] = {0.f, 0.f, 0.f, 0.f};
#pragma unroll
    for (int i = 0; i < 8; ++i) {
        int row = row0 + rg * 8 + i;
        float4 o;
        o.x = acc[i][0] + bv.x;
        o.y = acc[i][1] + bv.y;
        o.z = acc[i][2] + bv.z;
        o.w = acc[i][3] + bv.w;
        if (RELU) {
            o.x = fmaxf(o.x, 0.f); o.y = fmaxf(o.y, 0.f);
            o.z = fmaxf(o.z, 0.f); o.w = fmaxf(o.w, 0.f);
        }
        if (row < n) {
            *(float4*)(out + (size_t)row * DD + cg * 4) = o;
            if (STATS) {
                psum[0] += o.x; psum[1] += o.y; psum[2] += o.z; psum[3] += o.w;
                psq[0] += o.x * o.x; psq[1] += o.y * o.y;
                psq[2] += o.z * o.z; psq[3] += o.w * o.w;
            }
        }
    }
    if (STATS) {
        __syncthreads();
        atomicAdd(&Ssum[cg * 4 + 0], psum[0]);
        atomicAdd(&Ssum[cg * 4 + 1], psum[1]);
        atomicAdd(&Ssum[cg * 4 + 2], psum[2]);
        atomicAdd(&Ssum[cg * 4 + 3], psum[3]);
        atomicAdd(&Ssq[cg * 4 + 0], psq[0]);
        atomicAdd(&Ssq[cg * 4 + 1], psq[1]);
        atomicAdd(&Ssq[cg * 4 + 2], psq[2]);
        atomicAdd(&Ssq[cg * 4 + 3], psq[3]);
        __syncthreads();
        if (t < 128) {
            atomicAdd(&stats[t], Ssum[t]);
            atomicAdd(&stats[128 + t], Ssq[t]);
        }
    }
}

// ---------------- BN finalize ----------------
__global__ void bn_finalize(const float* __restrict__ stats,
                            const float* __restrict__ gamma,
                            const float* __restrict__ beta,
                            float* __restrict__ scsh, int n) {
    int c = threadIdx.x;
    float inv_n = 1.0f / (float)n;
    float mean = stats[c] * inv_n;
    float var = stats[128 + c] * inv_n - mean * mean;
    float sc = gamma[c] * rsqrtf(var + BN_EPS);
    scsh[c] = sc;
    scsh[128 + c] = beta[c] - mean * sc;
}

// ---------------- apply: out = h + leaky(z2*scale + shift) ----------------
__global__ void apply_kernel(const float* __restrict__ h,
                             const float* __restrict__ z2,
                             const float* __restrict__ scsh,
                             float* __restrict__ out, int total4) {
    int i = blockIdx.x * blockDim.x + threadIdx.x;
    if (i >= total4) return;
    int c4 = i & 31;
    float4 sc = ((const float4*)scsh)[c4];
    float4 sh = ((const float4*)(scsh + 128))[c4];
    float4 z = ((const float4*)z2)[i];
    float4 hh = ((const float4*)h)[i];
    float4 o;
    float v;
    v = fmaf(z.x, sc.x, sh.x); o.x = hh.x + (v >= 0.f ? v : SLOPE * v);
    v = fmaf(z.y, sc.y, sh.y); o.y = hh.y + (v >= 0.f ? v : SLOPE * v);
    v = fmaf(z.z, sc.z, sh.z); o.z = hh.z + (v >= 0.f ? v : SLOPE * v);
    v = fmaf(z.w, sc.w, sh.w); o.w = hh.w + (v >= 0.f ? v : SLOPE * v);
    ((float4*)out)[i] = o;
}

extern "C" void kernel_launch(void* const* d_in, const int* in_sizes, int n_in,
                              void* d_out, int out_size, void* d_ws, size_t ws_size,
                              hipStream_t stream) {
    const float* h     = (const float*)d_in[0];
    const int*   src   = (const int*)d_in[1];
    const int*   dst   = (const int*)d_in[2];
    const float* eps   = (const float*)d_in[3];
    const float* W1    = (const float*)d_in[4];
    const float* b1    = (const float*)d_in[5];
    const float* W2    = (const float*)d_in[6];
    const float* b2    = (const float*)d_in[7];
    const float* gamma = (const float*)d_in[8];
    const float* beta  = (const float*)d_in[9];
    float* out = (float*)d_out;

    const int n = in_sizes[0] / DD;   // 50000
    const int E = in_sizes[1];        // 1600000
    const int NB = (n + BROWS - 1) / BROWS;   // 782 buckets

    // workspace layout (floats)
    float* ws    = (float*)d_ws;
    float* agg0  = ws;                        // n*DD; partial 0, reused as z2
    float* z1    = ws + (size_t)n * DD;       // n*DD
    float* stats = ws + (size_t)2 * n * DD;   // 256
    float* scsh  = stats + 256;               // 256
    float* agg1  = out;                       // d_out as scratch: partial 1,
                                              // dead after GEMM1, rewritten by apply
    float* z2    = agg0;

    // scratch overlaid on z1 (dead until GEMM1 writes it)
    int* bcnt        = (int*)z1;
    int* off         = bcnt + NB;
    int* cursor      = off + NB + 1;
    unsigned* packed = (unsigned*)(cursor + (size_t)NB * CPAD);
    ushort* hb       = (ushort*)(packed + E);

    hipMemsetAsync(bcnt, 0, (size_t)NB * sizeof(int), stream);
    hipMemsetAsync(stats, 0, 256 * sizeof(float), stream);

    {   // h -> bf16
        int total4 = n * DD / 4;
        h2b_kernel<<<(total4 + 255) / 256, 256, 0, stream>>>(h, hb, total4);
    }
    {   // coarse bucket build
        histb_kernel<<<256, 256, 0, stream>>>(dst, bcnt, E, NB);
        scanb_kernel<<<1, 1024, 0, stream>>>(bcnt, off, cursor, NB);
        scatb2_kernel<<<(E + SCHUNK - 1) / SCHUNK, 256, 0, stream>>>(
            src, dst, cursor, packed, E, NB);
    }
    {   // split gather: 2 sub-blocks per bucket, wide loads
        aggb3_kernel<<<NB * 2, 256, 0, stream>>>(hb, off, packed, agg0, agg1, n);
    }
    {   // GEMM1: z1 = relu(((1+eps)h + agg0 + agg1) @ W1 + b1)
        int blocks = (n + 63) / 64;
        gemm_kernel<true, true, false><<<blocks, 256, 0, stream>>>(
            h, agg0, agg1, eps, W1, b1, z1, nullptr, n);
    }
    {   // GEMM2: z2 = z1 @ W2 + b2, with BN stats
        int blocks = (n + 63) / 64;
        gemm_kernel<false, false, true><<<blocks, 256, 0, stream>>>(
            z1, nullptr, nullptr, nullptr, W2, b2, z2, stats, n);
    }
    bn_finalize<<<1, 128, 0, stream>>>(stats, gamma, beta, scsh, n);
    {   // apply BN + leaky relu + residual
        int total4 = n * DD / 4;
        int blocks = (total4 + 255) / 256;
        apply_kernel<<<blocks, 256, 0, stream>>>(h, z2, scsh, out, total4);
    }
}

// Round 7
// 349.645 us; speedup vs baseline: 1.0801x; 1.0801x over previous
//
#include <hip/hip_runtime.h>
#include <cstddef>

#define DD 128
#define BN_EPS 1e-5f
#define SLOPE 0.01f
#define BSH 6              // 64 dst rows per bucket
#define BROWS 64
#define CPAD 16            // cursor padding (ints) -> one cacheline per cursor
#define CAP 4096           // aggb per-chunk edge capacity in LDS
#define SCHUNK 4096        // scatb per-block edge chunk
#define CSH 13             // src-chunk shift: 8192 rows = 2 MB bf16, L2-resident
#define NCH 7              // ceil(50000/8192)

typedef __attribute__((ext_vector_type(8))) short short8;
typedef __attribute__((ext_vector_type(4))) float float4v;

__device__ __forceinline__ unsigned short f2b(float x) {
    unsigned b = __float_as_uint(x);
    b += 0x7fffu + ((b >> 16) & 1u);   // round-to-nearest-even
    return (unsigned short)(b >> 16);
}
__device__ __forceinline__ void acc4(float4& a, uint2 u) {
    a.x += __uint_as_float(u.x << 16);
    a.y += __uint_as_float(u.x & 0xffff0000u);
    a.z += __uint_as_float(u.y << 16);
    a.w += __uint_as_float(u.y & 0xffff0000u);
}

// ---------- h (fp32) -> hb (bf16), RNE ----------
__global__ __launch_bounds__(256) void h2b_kernel(const float* __restrict__ h,
                                                  ushort* __restrict__ hb, int total4) {
    int i = blockIdx.x * blockDim.x + threadIdx.x;
    if (i >= total4) return;
    float4 v = ((const float4*)h)[i];
    ushort4 o;
    o.x = f2b(v.x); o.y = f2b(v.y); o.z = f2b(v.z); o.w = f2b(v.w);
    ((ushort4*)hb)[i] = o;
}

// ---------- bucket histogram ----------
__global__ __launch_bounds__(256) void histb_kernel(const int* __restrict__ dst,
                                                    int* __restrict__ bcnt,
                                                    int E, int NB) {
    __shared__ int bins[1024];
    for (int i = threadIdx.x; i < NB; i += blockDim.x) bins[i] = 0;
    __syncthreads();
    for (int e = blockIdx.x * blockDim.x + threadIdx.x; e < E;
         e += gridDim.x * blockDim.x)
        atomicAdd(&bins[dst[e] >> BSH], 1);
    __syncthreads();
    for (int i = threadIdx.x; i < NB; i += blockDim.x)
        if (bins[i]) atomicAdd(&bcnt[i], bins[i]);
}

// ---------- exclusive scan of bucket counts (NB <= 1024) ----------
__global__ __launch_bounds__(1024) void scanb_kernel(const int* __restrict__ bcnt,
                                                     int* __restrict__ off,
                                                     int* __restrict__ cursor, int NB) {
    __shared__ int s[1024];
    const int t = threadIdx.x;
    int v = (t < NB) ? bcnt[t] : 0;
    s[t] = v;
    __syncthreads();
    for (int d = 1; d < 1024; d <<= 1) {
        int u = (t >= d) ? s[t - d] : 0;
        __syncthreads();
        s[t] += u;
        __syncthreads();
    }
    if (t < NB) {
        int excl = s[t] - v;
        off[t] = excl;
        cursor[t * CPAD] = excl;
    }
    if (t == 0) off[NB] = s[1023];
}

// ---------- sorted chunk scatter ----------
__global__ __launch_bounds__(256) void scatb2_kernel(const int* __restrict__ src,
                                                     const int* __restrict__ dst,
                                                     int* __restrict__ cursor,
                                                     unsigned* __restrict__ packed,
                                                     int E, int NB) {
    __shared__ int bins[1024];
    __shared__ int lofs[1024];
    __shared__ int lcur[1024];
    __shared__ int gbase[1024];
    __shared__ unsigned sbuf[SCHUNK];
    __shared__ int wtot[4];

    const int t = threadIdx.x;
    const int lane = t & 63;
    const int w = t >> 6;
    const int cs = blockIdx.x * SCHUNK;
    const int cn = min(SCHUNK, E - cs);

#pragma unroll
    for (int k = 0; k < 4; ++k) bins[t + 256 * k] = 0;
    __syncthreads();
    for (int i = t; i < cn; i += 256) atomicAdd(&bins[dst[cs + i] >> BSH], 1);
    __syncthreads();

    const int b0 = 4 * t;
    int c0 = bins[b0], c1 = bins[b0 + 1], c2 = bins[b0 + 2], c3 = bins[b0 + 3];
    int s = c0 + c1 + c2 + c3;
    int si = s;
#pragma unroll
    for (int d = 1; d < 64; d <<= 1) {
        int u = __shfl_up(si, d);
        if (lane >= d) si += u;
    }
    if (lane == 63) wtot[w] = si;
    __syncthreads();
    if (t == 0) {
        int a = 0;
#pragma unroll
        for (int k = 0; k < 4; ++k) { int v = wtot[k]; wtot[k] = a; a += v; }
    }
    __syncthreads();
    int excl = wtot[w] + si - s;
    lofs[b0] = excl; lcur[b0] = excl;
    lofs[b0 + 1] = excl + c0; lcur[b0 + 1] = excl + c0;
    lofs[b0 + 2] = excl + c0 + c1; lcur[b0 + 2] = excl + c0 + c1;
    lofs[b0 + 3] = excl + c0 + c1 + c2; lcur[b0 + 3] = excl + c0 + c1 + c2;
    __syncthreads();

    for (int b = t; b < NB; b += 256) {
        int c = bins[b];
        if (c) gbase[b] = atomicAdd(&cursor[b * CPAD], c) - lofs[b];
    }
    for (int i = t; i < cn; i += 256) {
        int d = dst[cs + i];
        int b = d >> BSH;
        int pos = atomicAdd(&lcur[b], 1);
        sbuf[pos] = ((unsigned)b << 22) | ((unsigned)(d & (BROWS - 1)) << 16)
                    | (unsigned)src[cs + i];
    }
    __syncthreads();
    for (int i = t; i < cn; i += 256) {
        unsigned p = sbuf[i];
        int b = (int)(p >> 22);
        packed[gbase[b] + i] = p;
    }
}

// ---------- fused counting-sort + wide register gather, 512 threads ----------
// One block per bucket (preserves sort amortization + chunk-major L2 phasing,
// the R6 split broke both). 8 waves/block -> ~24 waves/CU. Wave owns 8 nodes;
// lanes 0..31 cover a full row as uint2; half-waves take alternate edges.
__global__ __launch_bounds__(512) void aggb4_kernel(const ushort* __restrict__ hb,
                                                    const int* __restrict__ off,
                                                    const unsigned* __restrict__ packed,
                                                    float* __restrict__ agg, int n) {
    __shared__ int bins[512];
    __shared__ int cofs[513];
    __shared__ int ccur[512];
    __shared__ unsigned short sbuf[CAP];
    __shared__ int wtot8[8];

    const int t = threadIdx.x;
    const int lane = t & 63;
    const int cg = lane & 31;
    const int hw = lane >> 5;
    const int w = t >> 6;        // 0..7
    const int b = blockIdx.x;
    const int e0 = off[b];
    const int e1 = off[b + 1];

    float4 acc[8];
#pragma unroll
    for (int i = 0; i < 8; ++i) acc[i] = make_float4(0.f, 0.f, 0.f, 0.f);

    for (int cs = e0; cs < e1; cs += CAP) {
        const int cn = min(CAP, e1 - cs);
        bins[t] = 0;
        __syncthreads();
        for (int i = t; i < cn; i += 512) {
            unsigned p = packed[cs + i];
            int key = (int)((((p & 0xffffu) >> CSH) << 6) | ((p >> 16) & 63u));
            atomicAdd(&bins[key], 1);
        }
        __syncthreads();
        int v = bins[t];
        int si = v;
#pragma unroll
        for (int d = 1; d < 64; d <<= 1) {
            int u = __shfl_up(si, d);
            if (lane >= d) si += u;
        }
        if (lane == 63) wtot8[w] = si;
        __syncthreads();
        if (t == 0) {
            int a = 0;
#pragma unroll
            for (int k = 0; k < 8; ++k) { int x = wtot8[k]; wtot8[k] = a; a += x; }
        }
        __syncthreads();
        int excl = wtot8[w] + si - v;
        cofs[t] = excl; ccur[t] = excl;
        if (t == 511) cofs[512] = excl + v;
        __syncthreads();
        for (int i = t; i < cn; i += 512) {
            unsigned p = packed[cs + i];
            int key = (int)((((p & 0xffffu) >> CSH) << 6) | ((p >> 16) & 63u));
            int pos = atomicAdd(&ccur[key], 1);
            sbuf[pos] = (unsigned short)(p & 0xffffu);
        }
        __syncthreads();

        for (int c = 0; c < NCH; ++c) {
            const int kbase = c * 64 + w * 8;
#pragma unroll
            for (int i = 0; i < 8; ++i) {
                const int jb = cofs[kbase + i];
                const int je = cofs[kbase + i + 1];
                float4 a = acc[i];
                int j = jb;
                for (; j + 8 <= je; j += 8) {
                    int s0 = sbuf[j + 0 + hw];
                    int s1 = sbuf[j + 2 + hw];
                    int s2 = sbuf[j + 4 + hw];
                    int s3 = sbuf[j + 6 + hw];
                    uint2 u0 = ((const uint2*)(hb + (size_t)s0 * DD))[cg];
                    uint2 u1 = ((const uint2*)(hb + (size_t)s1 * DD))[cg];
                    uint2 u2 = ((const uint2*)(hb + (size_t)s2 * DD))[cg];
                    uint2 u3 = ((const uint2*)(hb + (size_t)s3 * DD))[cg];
                    acc4(a, u0); acc4(a, u1); acc4(a, u2); acc4(a, u3);
                }
                for (; j + 2 <= je; j += 2) {
                    int s0 = sbuf[j + hw];
                    uint2 u0 = ((const uint2*)(hb + (size_t)s0 * DD))[cg];
                    acc4(a, u0);
                }
                if (j < je && hw == 0) {
                    int s0 = sbuf[j];
                    uint2 u0 = ((const uint2*)(hb + (size_t)s0 * DD))[cg];
                    acc4(a, u0);
                }
                acc[i] = a;
            }
        }
        __syncthreads();
    }

    const int r0 = b << BSH;
#pragma unroll
    for (int i = 0; i < 8; ++i) {
        float4 a = acc[i];
        a.x += __shfl_down(a.x, 32);
        a.y += __shfl_down(a.y, 32);
        a.z += __shfl_down(a.z, 32);
        a.w += __shfl_down(a.w, 32);
        int u = r0 + w * 8 + i;
        if (hw == 0 && u < n)
            ((float4*)(agg + (size_t)u * DD))[cg] = a;
    }
}

// ---------------- MFMA GEMM: 64 rows x 128 cols per block, K=128 ----------
// MODE 0: A = bf16((1+eps)*A0 + A1), out = bf16(relu(A@W + bias))  [z1b]
// MODE 1: A = Ab (bf16), out = fp32(A@W + bias) + column stats     [z2]
// Fragment layouts (m89-verified): A[m=lane&15][k=quad*8+j],
// B[k=quad*8+j][n=lane&15] (W staged transposed), C/D col=lane&15,
// row=quad*4+reg. Row pad 136 bf16 (272 B = 16*17) keeps ds_read_b128
// aligned with only 2-way bank aliasing (free).
template <int MODE>
__global__ __launch_bounds__(256) void mgemm_kernel(
        const float* __restrict__ A0, const float* __restrict__ A1,
        const ushort* __restrict__ Ab, const float* __restrict__ eps_ptr,
        const float* __restrict__ W, const float* __restrict__ bias,
        ushort* __restrict__ outb, float* __restrict__ outf,
        float* __restrict__ stats, int n) {
    __shared__ ushort As[64][136];
    __shared__ ushort Ws[128][136];
    __shared__ float Ssum[128];
    __shared__ float Ssq[128];

    const int t = threadIdx.x;
    const int lane = t & 63;
    const int w = t >> 6;
    const int quad = lane >> 4;
    const int l16 = lane & 15;
    const int row0 = blockIdx.x * 64;

    if (MODE == 1 && t < 128) { Ssum[t] = 0.f; Ssq[t] = 0.f; }

    // stage W transposed: Ws[c][k] = bf16(W[k][c])
#pragma unroll
    for (int jj = 0; jj < 16; ++jj) {
        int f = jj * 256 + t;            // float4 id in [0,4096)
        int k = f >> 5;
        int c = (f & 31) * 4;
        float4 v = ((const float4*)W)[f];
        Ws[c + 0][k] = f2b(v.x);
        Ws[c + 1][k] = f2b(v.y);
        Ws[c + 2][k] = f2b(v.z);
        Ws[c + 3][k] = f2b(v.w);
    }

    if (MODE == 0) {
        const float epsval = 1.0f + *eps_ptr;
#pragma unroll
        for (int jj = 0; jj < 8; ++jj) {
            int p = jj * 256 + t;        // float4 pos in [0,2048): 64 rows x 32
            int r = p >> 5;
            int c4 = p & 31;
            int row = row0 + r;
            ushort4 o = make_ushort4(0, 0, 0, 0);
            if (row < n) {
                float4 a = *((const float4*)(A0 + (size_t)row * DD) + c4);
                float4 g = *((const float4*)(A1 + (size_t)row * DD) + c4);
                o.x = f2b(epsval * a.x + g.x);
                o.y = f2b(epsval * a.y + g.y);
                o.z = f2b(epsval * a.z + g.z);
                o.w = f2b(epsval * a.w + g.w);
            }
            *(ushort4*)&As[r][c4 * 4] = o;
        }
    } else {
#pragma unroll
        for (int jj = 0; jj < 4; ++jj) {
            int p = jj * 256 + t;        // ushort8 pos in [0,1024): 64 rows x 16
            int r = p >> 4;
            int c8 = p & 15;
            int row = row0 + r;
            uint4 v = make_uint4(0, 0, 0, 0);
            if (row < n)
                v = *((const uint4*)(Ab + (size_t)row * DD) + c8);
            *(uint4*)&As[r][c8 * 8] = v;
        }
    }
    __syncthreads();

    // A fragments for all 4 k-blocks (each: 8 contiguous bf16 = ds_read_b128)
    short8 afr[4];
    const ushort* arow = &As[w * 16 + l16][0];
#pragma unroll
    for (int k = 0; k < 4; ++k)
        afr[k] = *(const short8*)(arow + k * 32 + quad * 8);

    float4v acc[8];
#pragma unroll
    for (int i = 0; i < 8; ++i) acc[i] = (float4v)(0.f);

#pragma unroll
    for (int nt = 0; nt < 8; ++nt) {
        const ushort* brow = &Ws[nt * 16 + l16][0];
#pragma unroll
        for (int k = 0; k < 4; ++k) {
            short8 bfr = *(const short8*)(brow + k * 32 + quad * 8);
            acc[nt] = __builtin_amdgcn_mfma_f32_16x16x32_bf16(afr[k], bfr, acc[nt], 0, 0, 0);
        }
    }

    if (MODE == 0) {
#pragma unroll
        for (int nt = 0; nt < 8; ++nt) {
            float bv = bias[nt * 16 + l16];
#pragma unroll
            for (int r = 0; r < 4; ++r) {
                int row = row0 + w * 16 + quad * 4 + r;
                if (row < n) {
                    float o = fmaxf(acc[nt][r] + bv, 0.f);
                    outb[(size_t)row * DD + nt * 16 + l16] = f2b(o);
                }
            }
        }
    } else {
#pragma unroll
        for (int nt = 0; nt < 8; ++nt) {
            float bv = bias[nt * 16 + l16];
            float s = 0.f, q = 0.f;
#pragma unroll
            for (int r = 0; r < 4; ++r) {
                int row = row0 + w * 16 + quad * 4 + r;
                if (row < n) {
                    float o = acc[nt][r] + bv;
                    outf[(size_t)row * DD + nt * 16 + l16] = o;
                    s += o;
                    q += o * o;
                }
            }
            atomicAdd(&Ssum[nt * 16 + l16], s);
            atomicAdd(&Ssq[nt * 16 + l16], q);
        }
        __syncthreads();
        if (t < 128) {
            atomicAdd(&stats[t], Ssum[t]);
            atomicAdd(&stats[128 + t], Ssq[t]);
        }
    }
}

// ---------------- BN finalize ----------------
__global__ void bn_finalize(const float* __restrict__ stats,
                            const float* __restrict__ gamma,
                            const float* __restrict__ beta,
                            float* __restrict__ scsh, int n) {
    int c = threadIdx.x;
    float inv_n = 1.0f / (float)n;
    float mean = stats[c] * inv_n;
    float var = stats[128 + c] * inv_n - mean * mean;
    float sc = gamma[c] * rsqrtf(var + BN_EPS);
    scsh[c] = sc;
    scsh[128 + c] = beta[c] - mean * sc;
}

// ---------------- apply: out = h + leaky(z2*scale + shift) ----------------
__global__ void apply_kernel(const float* __restrict__ h,
                             const float* __restrict__ z2,
                             const float* __restrict__ scsh,
                             float* __restrict__ out, int total4) {
    int i = blockIdx.x * blockDim.x + threadIdx.x;
    if (i >= total4) return;
    int c4 = i & 31;
    float4 sc = ((const float4*)scsh)[c4];
    float4 sh = ((const float4*)(scsh + 128))[c4];
    float4 z = ((const float4*)z2)[i];
    float4 hh = ((const float4*)h)[i];
    float4 o;
    float v;
    v = fmaf(z.x, sc.x, sh.x); o.x = hh.x + (v >= 0.f ? v : SLOPE * v);
    v = fmaf(z.y, sc.y, sh.y); o.y = hh.y + (v >= 0.f ? v : SLOPE * v);
    v = fmaf(z.z, sc.z, sh.z); o.z = hh.z + (v >= 0.f ? v : SLOPE * v);
    v = fmaf(z.w, sc.w, sh.w); o.w = hh.w + (v >= 0.f ? v : SLOPE * v);
    ((float4*)out)[i] = o;
}

extern "C" void kernel_launch(void* const* d_in, const int* in_sizes, int n_in,
                              void* d_out, int out_size, void* d_ws, size_t ws_size,
                              hipStream_t stream) {
    const float* h     = (const float*)d_in[0];
    const int*   src   = (const int*)d_in[1];
    const int*   dst   = (const int*)d_in[2];
    const float* eps   = (const float*)d_in[3];
    const float* W1    = (const float*)d_in[4];
    const float* b1    = (const float*)d_in[5];
    const float* W2    = (const float*)d_in[6];
    const float* b2    = (const float*)d_in[7];
    const float* gamma = (const float*)d_in[8];
    const float* beta  = (const float*)d_in[9];
    float* out = (float*)d_out;

    const int n = in_sizes[0] / DD;   // 50000
    const int E = in_sizes[1];        // 1600000
    const int NB = (n + BROWS - 1) / BROWS;   // 782 buckets

    // workspace layout (floats)
    float* ws    = (float*)d_ws;
    float* agg   = ws;                        // n*DD fp32; reused as z2
    float* z1    = ws + (size_t)n * DD;       // n*DD region, multi-use
    float* stats = ws + (size_t)2 * n * DD;   // 256
    float* scsh  = stats + 256;               // 256
    float* z2    = agg;

    // z1 region overlay: hb first [0,12.8MB), then CSR scratch [12.8,19.3MB).
    // After aggb4 all of it is dead; mgemm1 writes z1b (bf16) over [0,12.8MB).
    ushort* hb       = (ushort*)z1;
    int* bcnt        = (int*)(hb + (size_t)n * DD);
    int* off         = bcnt + NB;
    int* cursor      = off + NB + 1;
    unsigned* packed = (unsigned*)(cursor + (size_t)NB * CPAD);
    ushort* z1b      = (ushort*)z1;

    hipMemsetAsync(bcnt, 0, (size_t)NB * sizeof(int), stream);
    hipMemsetAsync(stats, 0, 256 * sizeof(float), stream);

    {   // h -> bf16
        int total4 = n * DD / 4;
        h2b_kernel<<<(total4 + 255) / 256, 256, 0, stream>>>(h, hb, total4);
    }
    {   // coarse bucket build
        histb_kernel<<<256, 256, 0, stream>>>(dst, bcnt, E, NB);
        scanb_kernel<<<1, 1024, 0, stream>>>(bcnt, off, cursor, NB);
        scatb2_kernel<<<(E + SCHUNK - 1) / SCHUNK, 256, 0, stream>>>(
            src, dst, cursor, packed, E, NB);
    }
    {   // fused sort + gather, 512 threads/block
        aggb4_kernel<<<NB, 512, 0, stream>>>(hb, off, packed, agg, n);
    }
    {   // GEMM1 (MFMA): z1b = bf16(relu(((1+eps)h + agg) @ W1 + b1))
        int blocks = (n + 63) / 64;
        mgemm_kernel<0><<<blocks, 256, 0, stream>>>(
            h, agg, nullptr, eps, W1, b1, z1b, nullptr, nullptr, n);
    }
    {   // GEMM2 (MFMA): z2 = z1b @ W2 + b2, with BN stats
        int blocks = (n + 63) / 64;
        mgemm_kernel<1><<<blocks, 256, 0, stream>>>(
            nullptr, nullptr, z1b, nullptr, W2, b2, nullptr, z2, stats, n);
    }
    bn_finalize<<<1, 128, 0, stream>>>(stats, gamma, beta, scsh, n);
    {   // apply BN + leaky relu + residual
        int total4 = n * DD / 4;
        int blocks = (total4 + 255) / 256;
        apply_kernel<<<blocks, 256, 0, stream>>>(h, z2, scsh, out, total4);
    }
}

// Round 8
// 337.568 us; speedup vs baseline: 1.1187x; 1.0358x over previous
//
#include <hip/hip_runtime.h>
#include <cstddef>

#define DD 128
#define BN_EPS 1e-5f
#define SLOPE 0.01f
#define BSH 6              // 64 dst rows per bucket
#define BROWS 64
#define CPAD 16            // cursor padding (ints) -> one cacheline per cursor
#define CAP 4096           // aggb per-chunk edge capacity in LDS
#define SCHUNK 4096        // scatb per-block edge chunk
#define CSH 13             // src-chunk shift: 8192 rows = 2 MB bf16, L2-resident
#define NCH 7              // ceil(50000/8192)

typedef __attribute__((ext_vector_type(8))) short short8;
typedef __attribute__((ext_vector_type(4))) float float4v;

__device__ __forceinline__ unsigned short f2b(float x) {
    unsigned b = __float_as_uint(x);
    b += 0x7fffu + ((b >> 16) & 1u);   // round-to-nearest-even
    return (unsigned short)(b >> 16);
}
__device__ __forceinline__ float lo16(unsigned x) { return __uint_as_float(x << 16); }
__device__ __forceinline__ float hi16(unsigned x) { return __uint_as_float(x & 0xffff0000u); }

// ---------- prep: h->bf16, W1/W2 -> transposed bf16, bucket histogram ----------
__global__ __launch_bounds__(256) void prep_kernel(
        const float* __restrict__ h, ushort* __restrict__ hb,
        const float* __restrict__ W1, const float* __restrict__ W2,
        ushort* __restrict__ wt1, ushort* __restrict__ wt2,
        const int* __restrict__ dst, int* __restrict__ bcnt,
        int total4, int E, int NB) {
    const int gid = blockIdx.x * 256 + threadIdx.x;
    const int gstride = gridDim.x * 256;
    // h -> bf16
    for (int i = gid; i < total4; i += gstride) {
        float4 v = ((const float4*)h)[i];
        ushort4 o;
        o.x = f2b(v.x); o.y = f2b(v.y); o.z = f2b(v.z); o.w = f2b(v.w);
        ((ushort4*)hb)[i] = o;
    }
    // W transpose + convert (wt[c][k] = bf16(W[k][c]))
    for (int i = gid; i < 2 * DD * DD; i += gstride) {
        int wsel = i >> 14;
        int r = i & 16383;
        int c = r >> 7, k = r & 127;
        const float* Wsrc = wsel ? W2 : W1;
        ushort* Wdst = wsel ? wt2 : wt1;
        Wdst[c * DD + k] = f2b(Wsrc[k * DD + c]);
    }
    // bucket histogram
    __shared__ int bins[1024];
    for (int i = threadIdx.x; i < NB; i += 256) bins[i] = 0;
    __syncthreads();
    for (int e = gid; e < E; e += gstride) atomicAdd(&bins[dst[e] >> BSH], 1);
    __syncthreads();
    for (int i = threadIdx.x; i < NB; i += 256)
        if (bins[i]) atomicAdd(&bcnt[i], bins[i]);
}

// ---------- sorted chunk scatter (with in-block scan of bcnt) ----------
__global__ __launch_bounds__(256) void scatb3_kernel(
        const int* __restrict__ src, const int* __restrict__ dst,
        const int* __restrict__ bcnt, int* __restrict__ cursor,
        unsigned* __restrict__ packed, int E, int NB) {
    __shared__ int boff[1024];
    __shared__ int bins[1024];
    __shared__ int lofs[1024];
    __shared__ int lcur[1024];
    __shared__ int gbase[1024];
    __shared__ unsigned sbuf[SCHUNK];
    __shared__ int wtot[4];

    const int t = threadIdx.x;
    const int lane = t & 63;
    const int w = t >> 6;
    const int cs = blockIdx.x * SCHUNK;
    const int cn = min(SCHUNK, E - cs);

    // ---- in-block exclusive scan of bcnt -> boff (global bucket offsets) ----
    {
        const int b0 = 4 * t;
        int c0 = (b0 < NB) ? bcnt[b0] : 0;
        int c1 = (b0 + 1 < NB) ? bcnt[b0 + 1] : 0;
        int c2 = (b0 + 2 < NB) ? bcnt[b0 + 2] : 0;
        int c3 = (b0 + 3 < NB) ? bcnt[b0 + 3] : 0;
        int s = c0 + c1 + c2 + c3;
        int si = s;
#pragma unroll
        for (int d = 1; d < 64; d <<= 1) {
            int u = __shfl_up(si, d);
            if (lane >= d) si += u;
        }
        if (lane == 63) wtot[w] = si;
        __syncthreads();
        if (t == 0) {
            int a = 0;
#pragma unroll
            for (int k = 0; k < 4; ++k) { int v = wtot[k]; wtot[k] = a; a += v; }
        }
        __syncthreads();
        int excl = wtot[w] + si - s;
        boff[b0] = excl;
        boff[b0 + 1] = excl + c0;
        boff[b0 + 2] = excl + c0 + c1;
        boff[b0 + 3] = excl + c0 + c1 + c2;
    }

    // ---- local hist of this chunk ----
#pragma unroll
    for (int k = 0; k < 4; ++k) bins[t + 256 * k] = 0;
    __syncthreads();
    for (int i = t; i < cn; i += 256) atomicAdd(&bins[dst[cs + i] >> BSH], 1);
    __syncthreads();

    const int b0 = 4 * t;
    int c0 = bins[b0], c1 = bins[b0 + 1], c2 = bins[b0 + 2], c3 = bins[b0 + 3];
    int s = c0 + c1 + c2 + c3;
    int si = s;
#pragma unroll
    for (int d = 1; d < 64; d <<= 1) {
        int u = __shfl_up(si, d);
        if (lane >= d) si += u;
    }
    if (lane == 63) wtot[w] = si;
    __syncthreads();
    if (t == 0) {
        int a = 0;
#pragma unroll
        for (int k = 0; k < 4; ++k) { int v = wtot[k]; wtot[k] = a; a += v; }
    }
    __syncthreads();
    int excl = wtot[w] + si - s;
    lofs[b0] = excl; lcur[b0] = excl;
    lofs[b0 + 1] = excl + c0; lcur[b0 + 1] = excl + c0;
    lofs[b0 + 2] = excl + c0 + c1; lcur[b0 + 2] = excl + c0 + c1;
    lofs[b0 + 3] = excl + c0 + c1 + c2; lcur[b0 + 3] = excl + c0 + c1 + c2;
    __syncthreads();

    for (int b = t; b < NB; b += 256) {
        int c = bins[b];
        if (c) gbase[b] = boff[b] + atomicAdd(&cursor[b * CPAD], c) - lofs[b];
    }
    for (int i = t; i < cn; i += 256) {
        int d = dst[cs + i];
        int b = d >> BSH;
        int pos = atomicAdd(&lcur[b], 1);
        sbuf[pos] = ((unsigned)b << 22) | ((unsigned)(d & (BROWS - 1)) << 16)
                    | (unsigned)src[cs + i];
    }
    __syncthreads();
    for (int i = t; i < cn; i += 256) {
        unsigned p = sbuf[i];
        int b = (int)(p >> 22);
        packed[gbase[b] + i] = p;
    }
}

// ---------- fused counting-sort + quarter-wave uint4 gather, 1024 threads ----
// One block per bucket. Wave owns 4 nodes; quarter-wave qw handles edge
// j+qw; lane ql covers elements 8*ql..8*ql+7 of the row via one uint4
// (16 B x 16 lanes = full 256 B bf16 row; 4 edges = 1 KB per wave-instr).
__global__ __launch_bounds__(1024) void aggb5_kernel(
        const ushort* __restrict__ hb, const int* __restrict__ bcnt,
        const unsigned* __restrict__ packed, float* __restrict__ agg,
        int n, int NB) {
    __shared__ int sscan[1024];
    __shared__ int bins[512];
    __shared__ int cofs[513];
    __shared__ int ccur[512];
    __shared__ ushort sbuf[CAP];
    __shared__ int wtot[16];

    const int t = threadIdx.x;
    const int lane = t & 63;
    const int w = t >> 6;        // 0..15
    const int qw = lane >> 4;    // 0..3
    const int ql = lane & 15;
    const int b = blockIdx.x;

    // ---- in-block scan of bcnt -> e0,e1 ----
    {
        int v = (t < NB) ? bcnt[t] : 0;
        int si = v;
#pragma unroll
        for (int d = 1; d < 64; d <<= 1) {
            int u = __shfl_up(si, d);
            if (lane >= d) si += u;
        }
        if (lane == 63) wtot[w] = si;
        __syncthreads();
        if (t == 0) {
            int a = 0;
#pragma unroll
            for (int k = 0; k < 16; ++k) { int x = wtot[k]; wtot[k] = a; a += x; }
        }
        __syncthreads();
        sscan[t] = wtot[w] + si;
        __syncthreads();
    }
    const int e0 = (b == 0) ? 0 : sscan[b - 1];
    const int e1 = sscan[b];

    float a[4][8];
#pragma unroll
    for (int i = 0; i < 4; ++i)
#pragma unroll
        for (int k = 0; k < 8; ++k) a[i][k] = 0.f;

    for (int cs = e0; cs < e1; cs += CAP) {
        const int cn = min(CAP, e1 - cs);
        if (t < 512) bins[t] = 0;
        __syncthreads();
        for (int i = t; i < cn; i += 1024) {
            unsigned p = packed[cs + i];
            int key = (int)((((p & 0xffffu) >> CSH) << 6) | ((p >> 16) & 63u));
            atomicAdd(&bins[key], 1);
        }
        __syncthreads();
        // scan 512 bins with first 8 waves
        int bv = (t < 512) ? bins[t] : 0;
        int bsi = bv;
#pragma unroll
        for (int d = 1; d < 64; d <<= 1) {
            int u = __shfl_up(bsi, d);
            if (lane >= d) bsi += u;
        }
        if (t < 512 && lane == 63) wtot[w] = bsi;
        __syncthreads();
        if (t == 0) {
            int a2 = 0;
#pragma unroll
            for (int k = 0; k < 8; ++k) { int x = wtot[k]; wtot[k] = a2; a2 += x; }
        }
        __syncthreads();
        if (t < 512) {
            int excl = wtot[w] + bsi - bv;
            cofs[t] = excl; ccur[t] = excl;
            if (t == 511) cofs[512] = excl + bv;
        }
        __syncthreads();
        for (int i = t; i < cn; i += 1024) {
            unsigned p = packed[cs + i];
            int key = (int)((((p & 0xffffu) >> CSH) << 6) | ((p >> 16) & 63u));
            int pos = atomicAdd(&ccur[key], 1);
            sbuf[pos] = (unsigned short)(p & 0xffffu);
        }
        __syncthreads();

        for (int c = 0; c < NCH; ++c) {
            const int kbase = c * 64 + w * 4;
#pragma unroll
            for (int i = 0; i < 4; ++i) {
                const int jb = cofs[kbase + i];
                const int je = cofs[kbase + i + 1];
                for (int j = jb + qw; j < je; j += 4) {
                    int s = sbuf[j];
                    uint4 u = ((const uint4*)(hb + (size_t)s * DD))[ql];
                    a[i][0] += lo16(u.x); a[i][1] += hi16(u.x);
                    a[i][2] += lo16(u.y); a[i][3] += hi16(u.y);
                    a[i][4] += lo16(u.z); a[i][5] += hi16(u.z);
                    a[i][6] += lo16(u.w); a[i][7] += hi16(u.w);
                }
            }
        }
        __syncthreads();
    }

    const int r0 = b << BSH;
#pragma unroll
    for (int i = 0; i < 4; ++i) {
#pragma unroll
        for (int k = 0; k < 8; ++k) {
            a[i][k] += __shfl_down(a[i][k], 32);
            a[i][k] += __shfl_down(a[i][k], 16);
        }
        int u = r0 + w * 4 + i;
        if (qw == 0 && u < n) {
            float4 vlo = make_float4(a[i][0], a[i][1], a[i][2], a[i][3]);
            float4 vhi = make_float4(a[i][4], a[i][5], a[i][6], a[i][7]);
            ((float4*)(agg + (size_t)u * DD))[ql * 2] = vlo;
            ((float4*)(agg + (size_t)u * DD))[ql * 2 + 1] = vhi;
        }
    }
}

// ---------------- MFMA GEMM: 64 rows x 128 cols per block, K=128 ----------
// W arrives pre-transposed pre-converted (wt[c][k] bf16) from prep_kernel.
template <int MODE>
__global__ __launch_bounds__(256) void mgemm_kernel(
        const float* __restrict__ A0, const float* __restrict__ A1,
        const ushort* __restrict__ Ab, const float* __restrict__ eps_ptr,
        const ushort* __restrict__ wt, const float* __restrict__ bias,
        ushort* __restrict__ outb, float* __restrict__ outf,
        float* __restrict__ stats, int n) {
    __shared__ ushort As[64][136];
    __shared__ ushort Ws[128][136];
    __shared__ float Ssum[128];
    __shared__ float Ssq[128];

    const int t = threadIdx.x;
    const int lane = t & 63;
    const int w = t >> 6;
    const int quad = lane >> 4;
    const int l16 = lane & 15;
    const int row0 = blockIdx.x * 64;

    if (MODE == 1 && t < 128) { Ssum[t] = 0.f; Ssq[t] = 0.f; }

    // stage Wt: 2048 uint4 straight copies
#pragma unroll
    for (int jj = 0; jj < 8; ++jj) {
        int f = jj * 256 + t;
        int r = f >> 4, c8 = f & 15;
        *(uint4*)&Ws[r][c8 * 8] = ((const uint4*)wt)[f];
    }

    if (MODE == 0) {
        const float epsval = 1.0f + *eps_ptr;
#pragma unroll
        for (int jj = 0; jj < 8; ++jj) {
            int p = jj * 256 + t;
            int r = p >> 5;
            int c4 = p & 31;
            int row = row0 + r;
            ushort4 o = make_ushort4(0, 0, 0, 0);
            if (row < n) {
                float4 av = *((const float4*)(A0 + (size_t)row * DD) + c4);
                float4 g = *((const float4*)(A1 + (size_t)row * DD) + c4);
                o.x = f2b(epsval * av.x + g.x);
                o.y = f2b(epsval * av.y + g.y);
                o.z = f2b(epsval * av.z + g.z);
                o.w = f2b(epsval * av.w + g.w);
            }
            *(ushort4*)&As[r][c4 * 4] = o;
        }
    } else {
#pragma unroll
        for (int jj = 0; jj < 4; ++jj) {
            int p = jj * 256 + t;
            int r = p >> 4;
            int c8 = p & 15;
            int row = row0 + r;
            uint4 v = make_uint4(0, 0, 0, 0);
            if (row < n)
                v = *((const uint4*)(Ab + (size_t)row * DD) + c8);
            *(uint4*)&As[r][c8 * 8] = v;
        }
    }
    __syncthreads();

    short8 afr[4];
    const ushort* arow = &As[w * 16 + l16][0];
#pragma unroll
    for (int k = 0; k < 4; ++k)
        afr[k] = *(const short8*)(arow + k * 32 + quad * 8);

    float4v acc[8];
#pragma unroll
    for (int i = 0; i < 8; ++i) acc[i] = (float4v)(0.f);

#pragma unroll
    for (int nt = 0; nt < 8; ++nt) {
        const ushort* brow = &Ws[nt * 16 + l16][0];
#pragma unroll
        for (int k = 0; k < 4; ++k) {
            short8 bfr = *(const short8*)(brow + k * 32 + quad * 8);
            acc[nt] = __builtin_amdgcn_mfma_f32_16x16x32_bf16(afr[k], bfr, acc[nt], 0, 0, 0);
        }
    }

    if (MODE == 0) {
#pragma unroll
        for (int nt = 0; nt < 8; ++nt) {
            float bv = bias[nt * 16 + l16];
#pragma unroll
            for (int r = 0; r < 4; ++r) {
                int row = row0 + w * 16 + quad * 4 + r;
                if (row < n) {
                    float o = fmaxf(acc[nt][r] + bv, 0.f);
                    outb[(size_t)row * DD + nt * 16 + l16] = f2b(o);
                }
            }
        }
    } else {
#pragma unroll
        for (int nt = 0; nt < 8; ++nt) {
            float bv = bias[nt * 16 + l16];
            float s = 0.f, q = 0.f;
#pragma unroll
            for (int r = 0; r < 4; ++r) {
                int row = row0 + w * 16 + quad * 4 + r;
                if (row < n) {
                    float o = acc[nt][r] + bv;
                    outf[(size_t)row * DD + nt * 16 + l16] = o;
                    s += o;
                    q += o * o;
                }
            }
            atomicAdd(&Ssum[nt * 16 + l16], s);
            atomicAdd(&Ssq[nt * 16 + l16], q);
        }
        __syncthreads();
        if (t < 128) {
            atomicAdd(&stats[t], Ssum[t]);
            atomicAdd(&stats[128 + t], Ssq[t]);
        }
    }
}

// ---------------- apply (+ BN finalize in-block) ----------------
__global__ __launch_bounds__(256) void applybn_kernel(
        const float* __restrict__ h, const float* __restrict__ z2,
        const float* __restrict__ stats, const float* __restrict__ gamma,
        const float* __restrict__ beta, float* __restrict__ out,
        int n, int total4) {
    __shared__ float sc[128];
    __shared__ float sh[128];
    const int t = threadIdx.x;
    if (t < 128) {
        float inv_n = 1.0f / (float)n;
        float mean = stats[t] * inv_n;
        float var = stats[128 + t] * inv_n - mean * mean;
        float s = gamma[t] * rsqrtf(var + BN_EPS);
        sc[t] = s;
        sh[t] = beta[t] - mean * s;
    }
    __syncthreads();
    for (int i = blockIdx.x * 256 + t; i < total4; i += gridDim.x * 256) {
        int c4 = i & 31;
        float4 scv = ((const float4*)sc)[c4];
        float4 shv = ((const float4*)sh)[c4];
        float4 z = ((const float4*)z2)[i];
        float4 hh = ((const float4*)h)[i];
        float4 o;
        float v;
        v = fmaf(z.x, scv.x, shv.x); o.x = hh.x + (v >= 0.f ? v : SLOPE * v);
        v = fmaf(z.y, scv.y, shv.y); o.y = hh.y + (v >= 0.f ? v : SLOPE * v);
        v = fmaf(z.z, scv.z, shv.z); o.z = hh.z + (v >= 0.f ? v : SLOPE * v);
        v = fmaf(z.w, scv.w, shv.w); o.w = hh.w + (v >= 0.f ? v : SLOPE * v);
        ((float4*)out)[i] = o;
    }
}

extern "C" void kernel_launch(void* const* d_in, const int* in_sizes, int n_in,
                              void* d_out, int out_size, void* d_ws, size_t ws_size,
                              hipStream_t stream) {
    const float* h     = (const float*)d_in[0];
    const int*   src   = (const int*)d_in[1];
    const int*   dst   = (const int*)d_in[2];
    const float* eps   = (const float*)d_in[3];
    const float* W1    = (const float*)d_in[4];
    const float* b1    = (const float*)d_in[5];
    const float* W2    = (const float*)d_in[6];
    const float* b2    = (const float*)d_in[7];
    const float* gamma = (const float*)d_in[8];
    const float* beta  = (const float*)d_in[9];
    float* out = (float*)d_out;

    const int n = in_sizes[0] / DD;   // 50000
    const int E = in_sizes[1];        // 1600000
    const int NB = (n + BROWS - 1) / BROWS;   // 782
    const int total4 = n * DD / 4;

    // workspace layout
    float* ws   = (float*)d_ws;
    float* agg  = ws;                         // n*DD fp32; reused as z2
    float* z1r  = ws + (size_t)n * DD;        // n*DD multi-use region
    float* z2   = agg;

    // z1 region overlay: hb | packed | bcnt | cursor | stats | wt1 | wt2
    ushort* hb       = (ushort*)z1r;
    unsigned* packed = (unsigned*)(hb + (size_t)n * DD);
    int* bcnt        = (int*)(packed + E);
    int* cursor      = bcnt + NB;                        // NB*CPAD ints
    float* stats     = (float*)(cursor + (size_t)NB * CPAD);  // 256 floats
    ushort* wt1      = (ushort*)(stats + 256);
    ushort* wt2      = wt1 + DD * DD;
    ushort* z1b      = hb;   // mgemm0 output overwrites hb (dead by then)

    // single memset covering bcnt + cursor + stats
    size_t zbytes = ((size_t)NB + (size_t)NB * CPAD) * sizeof(int) + 256 * sizeof(float);
    hipMemsetAsync(bcnt, 0, zbytes, stream);

    // K1: h->bf16, W->bf16^T, histogram
    prep_kernel<<<320, 256, 0, stream>>>(h, hb, W1, W2, wt1, wt2, dst, bcnt,
                                         total4, E, NB);
    // K2: sorted chunk scatter (in-block scan)
    scatb3_kernel<<<(E + SCHUNK - 1) / SCHUNK, 256, 0, stream>>>(
        src, dst, bcnt, cursor, packed, E, NB);
    // K3: fused sort + quarter-wave gather
    aggb5_kernel<<<NB, 1024, 0, stream>>>(hb, bcnt, packed, agg, n, NB);
    // K4: GEMM1 (MFMA): z1b = bf16(relu(((1+eps)h + agg) @ W1 + b1))
    mgemm_kernel<0><<<(n + 63) / 64, 256, 0, stream>>>(
        h, agg, nullptr, eps, wt1, b1, z1b, nullptr, nullptr, n);
    // K5: GEMM2 (MFMA): z2 = z1b @ W2 + b2, + BN stats
    mgemm_kernel<1><<<(n + 63) / 64, 256, 0, stream>>>(
        nullptr, nullptr, z1b, nullptr, wt2, b2, nullptr, z2, stats, n);
    // K6: BN finalize (in-block) + leaky relu + residual
    applybn_kernel<<<1024, 256, 0, stream>>>(h, z2, stats, gamma, beta, out,
                                             n, total4);
}

// Round 9
// 313.751 us; speedup vs baseline: 1.2036x; 1.0759x over previous
//
#include <hip/hip_runtime.h>
#include <cstddef>

#define DD 128
#define BN_EPS 1e-5f
#define SLOPE 0.01f
#define BSH 6              // 64 dst rows per bucket
#define BROWS 64
#define CAP 4096           // aggb per-pass edge capacity in LDS
#define SCHUNK 4096        // scatb per-block edge chunk
#define CSH 13             // src-chunk shift: 8192 rows = 2 MB bf16, L2-resident
#define NCH 7              // ceil(50000/8192)

typedef __attribute__((ext_vector_type(8))) short short8;
typedef __attribute__((ext_vector_type(4))) float float4v;

__device__ __forceinline__ unsigned short f2b(float x) {
    unsigned b = __float_as_uint(x);
    b += 0x7fffu + ((b >> 16) & 1u);   // round-to-nearest-even
    return (unsigned short)(b >> 16);
}
__device__ __forceinline__ float lo16(unsigned x) { return __uint_as_float(x << 16); }
__device__ __forceinline__ float hi16(unsigned x) { return __uint_as_float(x & 0xffff0000u); }

// ---------- prep: h->bf16, W1/W2 -> transposed bf16 ----------
__global__ __launch_bounds__(256) void prep_kernel(
        const float* __restrict__ h, ushort* __restrict__ hb,
        const float* __restrict__ W1, const float* __restrict__ W2,
        ushort* __restrict__ wt1, ushort* __restrict__ wt2, int total4) {
    const int gid = blockIdx.x * 256 + threadIdx.x;
    const int gstride = gridDim.x * 256;
    for (int i = gid; i < total4; i += gstride) {
        float4 v = ((const float4*)h)[i];
        ushort4 o;
        o.x = f2b(v.x); o.y = f2b(v.y); o.z = f2b(v.z); o.w = f2b(v.w);
        ((ushort4*)hb)[i] = o;
    }
    for (int i = gid; i < 2 * DD * DD; i += gstride) {
        int wsel = i >> 14;
        int r = i & 16383;
        int c = r >> 7, k = r & 127;
        const float* Wsrc = wsel ? W2 : W1;
        ushort* Wdst = wsel ? wt2 : wt1;
        Wdst[c * DD + k] = f2b(Wsrc[k * DD + c]);
    }
}

// ---------- scatb4: local counting sort, block-local coalesced writes ----------
// Block s sorts its 4096-edge chunk by bucket in LDS, writes the sorted chunk
// to packed[s*SCHUNK ...] (coalesced, block-private) plus per-(chunk,bucket)
// count and local-offset rows. No global atomics, no scattered stores.
__global__ __launch_bounds__(256) void scatb4_kernel(
        const int* __restrict__ src, const int* __restrict__ dst,
        int* __restrict__ cnt, int* __restrict__ lofs,
        unsigned* __restrict__ packed, int E, int NB) {
    __shared__ int bins[1024];
    __shared__ int lofs_l[1024];
    __shared__ int lcur[1024];
    __shared__ unsigned sbuf[SCHUNK];
    __shared__ int wtot[4];

    const int t = threadIdx.x;
    const int lane = t & 63;
    const int w = t >> 6;
    const int s = blockIdx.x;
    const int cs = s * SCHUNK;
    const int cn = min(SCHUNK, E - cs);

#pragma unroll
    for (int k = 0; k < 4; ++k) bins[t + 256 * k] = 0;
    __syncthreads();
    for (int i = t; i < cn; i += 256) atomicAdd(&bins[dst[cs + i] >> BSH], 1);
    __syncthreads();

    const int b0 = 4 * t;
    int c0 = bins[b0], c1 = bins[b0 + 1], c2 = bins[b0 + 2], c3 = bins[b0 + 3];
    int sm = c0 + c1 + c2 + c3;
    int si = sm;
#pragma unroll
    for (int d = 1; d < 64; d <<= 1) {
        int u = __shfl_up(si, d);
        if (lane >= d) si += u;
    }
    if (lane == 63) wtot[w] = si;
    __syncthreads();
    if (t == 0) {
        int a = 0;
#pragma unroll
        for (int k = 0; k < 4; ++k) { int v = wtot[k]; wtot[k] = a; a += v; }
    }
    __syncthreads();
    int excl = wtot[w] + si - sm;
    lofs_l[b0] = excl; lcur[b0] = excl;
    lofs_l[b0 + 1] = excl + c0; lcur[b0 + 1] = excl + c0;
    lofs_l[b0 + 2] = excl + c0 + c1; lcur[b0 + 2] = excl + c0 + c1;
    lofs_l[b0 + 3] = excl + c0 + c1 + c2; lcur[b0 + 3] = excl + c0 + c1 + c2;
    __syncthreads();

    // write descriptor rows (coalesced)
    for (int b = t; b < NB; b += 256) {
        cnt[(size_t)s * NB + b] = bins[b];
        lofs[(size_t)s * NB + b] = lofs_l[b];
    }
    // sort into LDS
    for (int i = t; i < cn; i += 256) {
        int d = dst[cs + i];
        int b = d >> BSH;
        int pos = atomicAdd(&lcur[b], 1);
        sbuf[pos] = ((unsigned)(d & (BROWS - 1)) << 16) | (unsigned)src[cs + i];
    }
    __syncthreads();
    // block-local coalesced write-out
    for (int i = t; i < cn; i += 256) packed[cs + i] = sbuf[i];
}

// ---------- aggb6: run-gather + single per-bucket sort + predicated gather ----
// One block per bucket. Assembles the bucket's edges by READING runs from the
// block-private sorted chunks (no scattered writes anywhere). Sorts once by
// key = src_chunk*16 + (ldst>>2) (112 bins). Wave w owns nodes w*4..w*4+3 and
// sweeps one contiguous segment per src-chunk with 4 predicated accumulators.
__global__ __launch_bounds__(1024) void aggb6_kernel(
        const ushort* __restrict__ hb, const int* __restrict__ cnt,
        const int* __restrict__ lofs, const unsigned* __restrict__ packed,
        float* __restrict__ agg, int n, int NB, int NS) {
    __shared__ int rcnt[512];
    __shared__ int rsoff[512];
    __shared__ int rpre[512];
    __shared__ int bins[128];
    __shared__ int cofs[129];
    __shared__ int ccur[128];
    __shared__ int wtot[16];
    __shared__ int etot;
    __shared__ unsigned sbufA[CAP];
    __shared__ unsigned sbufB[CAP];

    const int t = threadIdx.x;
    const int lane = t & 63;
    const int w = t >> 6;        // 0..15
    const int qw = lane >> 4;    // 0..3 quarter-wave
    const int ql = lane & 15;
    const int qwg = t >> 4;      // global quarter-wave id 0..63
    const int b = blockIdx.x;

    // load descriptor columns (strided; matrices are L2/L3-resident)
    if (t < 512) {
        if (t < NS) {
            rcnt[t] = cnt[(size_t)t * NB + b];
            rsoff[t] = lofs[(size_t)t * NB + b];
        } else {
            rcnt[t] = 0; rsoff[t] = 0;
        }
    }
    __syncthreads();
    // scan 512 run counts (first 8 waves)
    {
        int v = (t < 512) ? rcnt[t] : 0;
        int si = v;
#pragma unroll
        for (int d = 1; d < 64; d <<= 1) {
            int u = __shfl_up(si, d);
            if (lane >= d) si += u;
        }
        if (t < 512 && lane == 63) wtot[w] = si;
        __syncthreads();
        if (t == 0) {
            int a = 0;
#pragma unroll
            for (int k = 0; k < 8; ++k) { int x = wtot[k]; wtot[k] = a; a += x; }
        }
        __syncthreads();
        if (t < 512) rpre[t] = wtot[w] + si - v;
        if (t == 511) etot = wtot[7] + si;
        __syncthreads();
    }
    const int e_b = etot;

    float a[4][8];
#pragma unroll
    for (int i = 0; i < 4; ++i)
#pragma unroll
        for (int k = 0; k < 8; ++k) a[i][k] = 0.f;

    for (int p0 = 0; p0 < e_b; p0 += CAP) {
        const int cnp = min(CAP, e_b - p0);
        // stage 1: assemble edge window from runs (read-only global access)
        for (int s = qwg; s < NS; s += 64) {
            int rc = rcnt[s];
            if (rc == 0) continue;
            int rp = rpre[s];
            if (rp >= p0 + cnp || rp + rc <= p0) continue;
            int base = s * SCHUNK + rsoff[s];
            for (int o = ql; o < rc; o += 16) {
                int g = rp + o;
                if (g >= p0 && g < p0 + cnp) sbufA[g - p0] = packed[base + o];
            }
        }
        if (t < 128) bins[t] = 0;
        __syncthreads();
        // histogram: key = chunk*16 + (ldst>>2)
        for (int i = t; i < cnp; i += 1024) {
            unsigned e = sbufA[i];
            int key = (int)((((e & 0xffffu) >> CSH) << 4) | ((e >> 18) & 15u));
            atomicAdd(&bins[key], 1);
        }
        __syncthreads();
        // scan 128 bins with wave 0
        if (t < 64) {
            int c0 = bins[2 * t], c1 = bins[2 * t + 1];
            int sm = c0 + c1;
            int si = sm;
#pragma unroll
            for (int d = 1; d < 64; d <<= 1) {
                int u = __shfl_up(si, d);
                if (lane >= d) si += u;
            }
            int excl = si - sm;
            cofs[2 * t] = excl;          ccur[2 * t] = excl;
            cofs[2 * t + 1] = excl + c0; ccur[2 * t + 1] = excl + c0;
            if (t == 63) cofs[128] = si;
        }
        __syncthreads();
        // scatter to sorted buffer
        for (int i = t; i < cnp; i += 1024) {
            unsigned e = sbufA[i];
            int key = (int)((((e & 0xffffu) >> CSH) << 4) | ((e >> 18) & 15u));
            int pos = atomicAdd(&ccur[key], 1);
            sbufB[pos] = e;
        }
        __syncthreads();

        // gather: wave w sweeps segment (c, group w); 4 predicated accumulators
        for (int c = 0; c < NCH; ++c) {
            const int jb = cofs[c * 16 + w];
            const int je = cofs[c * 16 + w + 1];
#pragma unroll 2
            for (int j = jb + qw; j < je; j += 4) {
                unsigned e = sbufB[j];
                int own = (int)((e >> 16) & 3u);
                uint4 u = ((const uint4*)(hb + (size_t)(e & 0xffffu) * DD))[ql];
                float f0 = lo16(u.x), f1 = hi16(u.x);
                float f2 = lo16(u.y), f3 = hi16(u.y);
                float f4 = lo16(u.z), f5 = hi16(u.z);
                float f6 = lo16(u.w), f7 = hi16(u.w);
                float m0 = (own == 0) ? 1.f : 0.f;
                float m1 = (own == 1) ? 1.f : 0.f;
                float m2 = (own == 2) ? 1.f : 0.f;
                float m3 = (own == 3) ? 1.f : 0.f;
                a[0][0] = fmaf(m0, f0, a[0][0]); a[0][1] = fmaf(m0, f1, a[0][1]);
                a[0][2] = fmaf(m0, f2, a[0][2]); a[0][3] = fmaf(m0, f3, a[0][3]);
                a[0][4] = fmaf(m0, f4, a[0][4]); a[0][5] = fmaf(m0, f5, a[0][5]);
                a[0][6] = fmaf(m0, f6, a[0][6]); a[0][7] = fmaf(m0, f7, a[0][7]);
                a[1][0] = fmaf(m1, f0, a[1][0]); a[1][1] = fmaf(m1, f1, a[1][1]);
                a[1][2] = fmaf(m1, f2, a[1][2]); a[1][3] = fmaf(m1, f3, a[1][3]);
                a[1][4] = fmaf(m1, f4, a[1][4]); a[1][5] = fmaf(m1, f5, a[1][5]);
                a[1][6] = fmaf(m1, f6, a[1][6]); a[1][7] = fmaf(m1, f7, a[1][7]);
                a[2][0] = fmaf(m2, f0, a[2][0]); a[2][1] = fmaf(m2, f1, a[2][1]);
                a[2][2] = fmaf(m2, f2, a[2][2]); a[2][3] = fmaf(m2, f3, a[2][3]);
                a[2][4] = fmaf(m2, f4, a[2][4]); a[2][5] = fmaf(m2, f5, a[2][5]);
                a[2][6] = fmaf(m2, f6, a[2][6]); a[2][7] = fmaf(m2, f7, a[2][7]);
                a[3][0] = fmaf(m3, f0, a[3][0]); a[3][1] = fmaf(m3, f1, a[3][1]);
                a[3][2] = fmaf(m3, f2, a[3][2]); a[3][3] = fmaf(m3, f3, a[3][3]);
                a[3][4] = fmaf(m3, f4, a[3][4]); a[3][5] = fmaf(m3, f5, a[3][5]);
                a[3][6] = fmaf(m3, f6, a[3][6]); a[3][7] = fmaf(m3, f7, a[3][7]);
            }
        }
        __syncthreads();
    }

    const int r0 = b << BSH;
#pragma unroll
    for (int i = 0; i < 4; ++i) {
#pragma unroll
        for (int k = 0; k < 8; ++k) {
            a[i][k] += __shfl_down(a[i][k], 32);
            a[i][k] += __shfl_down(a[i][k], 16);
        }
        int u = r0 + w * 4 + i;
        if (qw == 0 && u < n) {
            float4 vlo = make_float4(a[i][0], a[i][1], a[i][2], a[i][3]);
            float4 vhi = make_float4(a[i][4], a[i][5], a[i][6], a[i][7]);
            ((float4*)(agg + (size_t)u * DD))[ql * 2] = vlo;
            ((float4*)(agg + (size_t)u * DD))[ql * 2 + 1] = vhi;
        }
    }
}

// ---------------- MFMA GEMM: 64 rows x 128 cols per block, K=128 ----------
template <int MODE>
__global__ __launch_bounds__(256) void mgemm_kernel(
        const float* __restrict__ A0, const float* __restrict__ A1,
        const ushort* __restrict__ Ab, const float* __restrict__ eps_ptr,
        const ushort* __restrict__ wt, const float* __restrict__ bias,
        ushort* __restrict__ outb, float* __restrict__ outf,
        float* __restrict__ stats, int n) {
    __shared__ ushort As[64][136];
    __shared__ ushort Ws[128][136];
    __shared__ float Ssum[128];
    __shared__ float Ssq[128];

    const int t = threadIdx.x;
    const int lane = t & 63;
    const int w = t >> 6;
    const int quad = lane >> 4;
    const int l16 = lane & 15;
    const int row0 = blockIdx.x * 64;

    if (MODE == 1 && t < 128) { Ssum[t] = 0.f; Ssq[t] = 0.f; }

#pragma unroll
    for (int jj = 0; jj < 8; ++jj) {
        int f = jj * 256 + t;
        int r = f >> 4, c8 = f & 15;
        *(uint4*)&Ws[r][c8 * 8] = ((const uint4*)wt)[f];
    }

    if (MODE == 0) {
        const float epsval = 1.0f + *eps_ptr;
#pragma unroll
        for (int jj = 0; jj < 8; ++jj) {
            int p = jj * 256 + t;
            int r = p >> 5;
            int c4 = p & 31;
            int row = row0 + r;
            ushort4 o = make_ushort4(0, 0, 0, 0);
            if (row < n) {
                float4 av = *((const float4*)(A0 + (size_t)row * DD) + c4);
                float4 g = *((const float4*)(A1 + (size_t)row * DD) + c4);
                o.x = f2b(epsval * av.x + g.x);
                o.y = f2b(epsval * av.y + g.y);
                o.z = f2b(epsval * av.z + g.z);
                o.w = f2b(epsval * av.w + g.w);
            }
            *(ushort4*)&As[r][c4 * 4] = o;
        }
    } else {
#pragma unroll
        for (int jj = 0; jj < 4; ++jj) {
            int p = jj * 256 + t;
            int r = p >> 4;
            int c8 = p & 15;
            int row = row0 + r;
            uint4 v = make_uint4(0, 0, 0, 0);
            if (row < n)
                v = *((const uint4*)(Ab + (size_t)row * DD) + c8);
            *(uint4*)&As[r][c8 * 8] = v;
        }
    }
    __syncthreads();

    short8 afr[4];
    const ushort* arow = &As[w * 16 + l16][0];
#pragma unroll
    for (int k = 0; k < 4; ++k)
        afr[k] = *(const short8*)(arow + k * 32 + quad * 8);

    float4v acc[8];
#pragma unroll
    for (int i = 0; i < 8; ++i) acc[i] = (float4v)(0.f);

#pragma unroll
    for (int nt = 0; nt < 8; ++nt) {
        const ushort* brow = &Ws[nt * 16 + l16][0];
#pragma unroll
        for (int k = 0; k < 4; ++k) {
            short8 bfr = *(const short8*)(brow + k * 32 + quad * 8);
            acc[nt] = __builtin_amdgcn_mfma_f32_16x16x32_bf16(afr[k], bfr, acc[nt], 0, 0, 0);
        }
    }

    if (MODE == 0) {
#pragma unroll
        for (int nt = 0; nt < 8; ++nt) {
            float bv = bias[nt * 16 + l16];
#pragma unroll
            for (int r = 0; r < 4; ++r) {
                int row = row0 + w * 16 + quad * 4 + r;
                if (row < n) {
                    float o = fmaxf(acc[nt][r] + bv, 0.f);
                    outb[(size_t)row * DD + nt * 16 + l16] = f2b(o);
                }
            }
        }
    } else {
#pragma unroll
        for (int nt = 0; nt < 8; ++nt) {
            float bv = bias[nt * 16 + l16];
            float s = 0.f, q = 0.f;
#pragma unroll
            for (int r = 0; r < 4; ++r) {
                int row = row0 + w * 16 + quad * 4 + r;
                if (row < n) {
                    float o = acc[nt][r] + bv;
                    outf[(size_t)row * DD + nt * 16 + l16] = o;
                    s += o;
                    q += o * o;
                }
            }
            atomicAdd(&Ssum[nt * 16 + l16], s);
            atomicAdd(&Ssq[nt * 16 + l16], q);
        }
        __syncthreads();
        if (t < 128) {
            atomicAdd(&stats[t], Ssum[t]);
            atomicAdd(&stats[128 + t], Ssq[t]);
        }
    }
}

// ---------------- apply (+ BN finalize in-block) ----------------
__global__ __launch_bounds__(256) void applybn_kernel(
        const float* __restrict__ h, const float* __restrict__ z2,
        const float* __restrict__ stats, const float* __restrict__ gamma,
        const float* __restrict__ beta, float* __restrict__ out,
        int n, int total4) {
    __shared__ float sc[128];
    __shared__ float sh[128];
    const int t = threadIdx.x;
    if (t < 128) {
        float inv_n = 1.0f / (float)n;
        float mean = stats[t] * inv_n;
        float var = stats[128 + t] * inv_n - mean * mean;
        float s = gamma[t] * rsqrtf(var + BN_EPS);
        sc[t] = s;
        sh[t] = beta[t] - mean * s;
    }
    __syncthreads();
    for (int i = blockIdx.x * 256 + t; i < total4; i += gridDim.x * 256) {
        int c4 = i & 31;
        float4 scv = ((const float4*)sc)[c4];
        float4 shv = ((const float4*)sh)[c4];
        float4 z = ((const float4*)z2)[i];
        float4 hh = ((const float4*)h)[i];
        float4 o;
        float v;
        v = fmaf(z.x, scv.x, shv.x); o.x = hh.x + (v >= 0.f ? v : SLOPE * v);
        v = fmaf(z.y, scv.y, shv.y); o.y = hh.y + (v >= 0.f ? v : SLOPE * v);
        v = fmaf(z.z, scv.z, shv.z); o.z = hh.z + (v >= 0.f ? v : SLOPE * v);
        v = fmaf(z.w, scv.w, shv.w); o.w = hh.w + (v >= 0.f ? v : SLOPE * v);
        ((float4*)out)[i] = o;
    }
}

extern "C" void kernel_launch(void* const* d_in, const int* in_sizes, int n_in,
                              void* d_out, int out_size, void* d_ws, size_t ws_size,
                              hipStream_t stream) {
    const float* h     = (const float*)d_in[0];
    const int*   src   = (const int*)d_in[1];
    const int*   dst   = (const int*)d_in[2];
    const float* eps   = (const float*)d_in[3];
    const float* W1    = (const float*)d_in[4];
    const float* b1    = (const float*)d_in[5];
    const float* W2    = (const float*)d_in[6];
    const float* b2    = (const float*)d_in[7];
    const float* gamma = (const float*)d_in[8];
    const float* beta  = (const float*)d_in[9];
    float* out = (float*)d_out;

    const int n = in_sizes[0] / DD;   // 50000
    const int E = in_sizes[1];        // 1600000
    const int NB = (n + BROWS - 1) / BROWS;   // 782
    const int NS = (E + SCHUNK - 1) / SCHUNK; // 391
    const int total4 = n * DD / 4;

    // workspace layout
    float* ws   = (float*)d_ws;
    float* agg  = ws;                         // n*DD fp32; reused as z2
    float* z1r  = ws + (size_t)n * DD;        // n*DD multi-use region
    float* z2   = agg;

    // region overlay: hb | packed | cnt | lofs | stats | wt1 | wt2
    ushort* hb       = (ushort*)z1r;
    unsigned* packed = (unsigned*)(hb + (size_t)n * DD);
    int* cnt         = (int*)(packed + (size_t)NS * SCHUNK);
    int* lofs        = cnt + (size_t)NS * NB;
    float* stats     = (float*)(lofs + (size_t)NS * NB);
    ushort* wt1      = (ushort*)(stats + 256);
    ushort* wt2      = wt1 + DD * DD;
    ushort* z1b      = hb;   // mgemm0 output overwrites hb (dead by then)

    hipMemsetAsync(stats, 0, 256 * sizeof(float), stream);

    // K1: h->bf16, W->bf16^T
    prep_kernel<<<320, 256, 0, stream>>>(h, hb, W1, W2, wt1, wt2, total4);
    // K2: local sort, block-private coalesced writes + descriptor matrices
    scatb4_kernel<<<NS, 256, 0, stream>>>(src, dst, cnt, lofs, packed, E, NB);
    // K3: run-gather + per-bucket sort + predicated gather
    aggb6_kernel<<<NB, 1024, 0, stream>>>(hb, cnt, lofs, packed, agg, n, NB, NS);
    // K4: GEMM1 (MFMA): z1b = bf16(relu(((1+eps)h + agg) @ W1 + b1))
    mgemm_kernel<0><<<(n + 63) / 64, 256, 0, stream>>>(
        h, agg, nullptr, eps, wt1, b1, z1b, nullptr, nullptr, n);
    // K5: GEMM2 (MFMA): z2 = z1b @ W2 + b2, + BN stats
    mgemm_kernel<1><<<(n + 63) / 64, 256, 0, stream>>>(
        nullptr, nullptr, z1b, nullptr, wt2, b2, nullptr, z2, stats, n);
    // K6: BN finalize (in-block) + leaky relu + residual
    applybn_kernel<<<1024, 256, 0, stream>>>(h, z2, stats, gamma, beta, out,
                                             n, total4);
}

// Round 10
// 249.796 us; speedup vs baseline: 1.5118x; 1.2560x over previous
//
#include <hip/hip_runtime.h>
#include <cstddef>

#define DD 128
#define BN_EPS 1e-5f
#define SLOPE 0.01f
#define BSH 6              // 64 dst rows per bucket
#define BROWS 64
#define CAP 4096           // aggemm per-window edge capacity in LDS
#define SCHUNK 8192        // scatb per-block edge chunk (longer runs -> cheap assembly)
#define CSH 13             // src-chunk shift: 8192 rows = 2 MB bf16, L2-resident
#define NCH 7              // ceil(50000/8192)

typedef __attribute__((ext_vector_type(8))) short short8;
typedef __attribute__((ext_vector_type(4))) float float4v;

__device__ __forceinline__ unsigned short f2b(float x) {
    unsigned b = __float_as_uint(x);
    b += 0x7fffu + ((b >> 16) & 1u);   // round-to-nearest-even
    return (unsigned short)(b >> 16);
}
__device__ __forceinline__ float lo16(unsigned x) { return __uint_as_float(x << 16); }
__device__ __forceinline__ float hi16(unsigned x) { return __uint_as_float(x & 0xffff0000u); }

// ---------- K1: fused prep (h->bf16, W->bf16^T) + local chunk sort ----------
// Block s sorts its 8192-edge chunk by bucket in LDS, writes the sorted chunk
// block-private (coalesced, no global atomics) + per-(chunk,bucket) cnt/lofs.
__global__ __launch_bounds__(1024) void scatb5_kernel(
        const float* __restrict__ h, ushort* __restrict__ hb,
        const float* __restrict__ W1, const float* __restrict__ W2,
        ushort* __restrict__ wt1, ushort* __restrict__ wt2,
        const int* __restrict__ src, const int* __restrict__ dst,
        int* __restrict__ cnt, int* __restrict__ lofs,
        unsigned* __restrict__ packed, int total4, int E, int NB) {
    __shared__ int bins[1024];
    __shared__ int lcur[1024];
    __shared__ int wtot[16];
    __shared__ unsigned sbuf[SCHUNK];

    const int t = threadIdx.x;
    const int lane = t & 63;
    const int w = t >> 6;
    const int s = blockIdx.x;
    const int cs = s * SCHUNK;
    const int cn = min(SCHUNK, E - cs);
    const int gid = s * 1024 + t;
    const int gstride = gridDim.x * 1024;

    // fused prep: h -> bf16
    for (int i = gid; i < total4; i += gstride) {
        float4 v = ((const float4*)h)[i];
        ushort4 o;
        o.x = f2b(v.x); o.y = f2b(v.y); o.z = f2b(v.z); o.w = f2b(v.w);
        ((ushort4*)hb)[i] = o;
    }
    // fused prep: W transpose+convert (wt[c][k] = bf16(W[k][c]))
    for (int i = gid; i < 2 * DD * DD; i += gstride) {
        int wsel = i >> 14;
        int r = i & 16383;
        int c = r >> 7, k = r & 127;
        const float* Wsrc = wsel ? W2 : W1;
        ushort* Wdst = wsel ? wt2 : wt1;
        Wdst[c * DD + k] = f2b(Wsrc[k * DD + c]);
    }

    // chunk histogram by bucket
    bins[t] = 0;
    __syncthreads();
    for (int i = t; i < cn; i += 1024) atomicAdd(&bins[dst[cs + i] >> BSH], 1);
    __syncthreads();
    // scan 1024 bins (16 waves)
    int v = bins[t];
    int si = v;
#pragma unroll
    for (int d = 1; d < 64; d <<= 1) {
        int u = __shfl_up(si, d);
        if (lane >= d) si += u;
    }
    if (lane == 63) wtot[w] = si;
    __syncthreads();
    if (t == 0) {
        int a = 0;
#pragma unroll
        for (int k = 0; k < 16; ++k) { int x = wtot[k]; wtot[k] = a; a += x; }
    }
    __syncthreads();
    int excl = wtot[w] + si - v;
    lcur[t] = excl;
    // descriptor rows (coalesced)
    if (t < NB) {
        cnt[(size_t)s * NB + t] = v;
        lofs[(size_t)s * NB + t] = excl;
    }
    __syncthreads();
    // sort into LDS
    for (int i = t; i < cn; i += 1024) {
        int d = dst[cs + i];
        int b = d >> BSH;
        int pos = atomicAdd(&lcur[b], 1);
        sbuf[pos] = ((unsigned)(d & (BROWS - 1)) << 16) | (unsigned)src[cs + i];
    }
    __syncthreads();
    // block-private coalesced write-out
    for (int i = t; i < cn; i += 1024) packed[cs + i] = sbuf[i];
}

// ---------- K2: fused gather + GEMM1 ----------
// One block per 64-node bucket. Phase A (aggb5-style): assemble runs, sort by
// (src_chunk, ldst), quarter-wave uint4 gather into registers. Phase B: build
// bf16 A-tile = (1+eps)*hb + agg in LDS (reusing phase-A smem), stage W1^T,
// 32 MFMAs, relu+bias, write z1b. agg never touches global memory.
__global__ __launch_bounds__(1024, 8) void aggemm_kernel(
        const ushort* __restrict__ hb, const int* __restrict__ cnt,
        const int* __restrict__ lofs, const unsigned* __restrict__ packed,
        const float* __restrict__ eps_ptr, const ushort* __restrict__ wt,
        const float* __restrict__ bias, ushort* __restrict__ z1b,
        int n, int NB, int NS) {
    __shared__ __align__(16) char smem[52224];
    __shared__ int wtot[16];
    __shared__ int etot;

    // phase A overlay
    int* rcnt  = (int*)smem;                       // 256
    int* rsoff = rcnt + 256;                       // 256
    int* rpre  = rsoff + 256;                      // 256
    int* bins  = rpre + 256;                       // 512
    int* cofs  = bins + 512;                       // 513
    int* ccur  = cofs + 513;                       // 512 (ends at 9220 B)
    unsigned* sbufA = (unsigned*)(smem + 9728);    // 16384 B
    ushort*  sbufB  = (ushort*)(smem + 26112);     // 8192 B

    const int t = threadIdx.x;
    const int lane = t & 63;
    const int w = t >> 6;        // 0..15
    const int qw = lane >> 4;    // 0..3
    const int ql = lane & 15;
    const int qwg = t >> 4;      // 0..63
    const int b = blockIdx.x;
    const float epsval = 1.0f + *eps_ptr;

    // descriptor load + scan (NS <= 256, 4 waves)
    if (t < 256) {
        if (t < NS) {
            rcnt[t] = cnt[(size_t)t * NB + b];
            rsoff[t] = lofs[(size_t)t * NB + b];
        } else { rcnt[t] = 0; rsoff[t] = 0; }
    }
    __syncthreads();
    {
        int v = (t < 256) ? rcnt[t] : 0;
        int si = v;
#pragma unroll
        for (int d = 1; d < 64; d <<= 1) {
            int u = __shfl_up(si, d);
            if (lane >= d) si += u;
        }
        if (t < 256 && lane == 63) wtot[w] = si;
        __syncthreads();
        if (t == 0) {
            int a = 0;
#pragma unroll
            for (int k = 0; k < 4; ++k) { int x = wtot[k]; wtot[k] = a; a += x; }
        }
        __syncthreads();
        if (t < 256) rpre[t] = wtot[w] + si - v;
        if (t == 255) etot = wtot[3] + si;
        __syncthreads();
    }
    const int e_b = etot;

    float a[4][8];
#pragma unroll
    for (int i = 0; i < 4; ++i)
#pragma unroll
        for (int k = 0; k < 8; ++k) a[i][k] = 0.f;

    for (int p0 = 0; p0 < e_b; p0 += CAP) {
        const int cnp = min(CAP, e_b - p0);
        // assemble window from block-private runs (read-only)
        for (int s = qwg; s < NS; s += 64) {
            int rc = rcnt[s];
            if (rc == 0) continue;
            int rp = rpre[s];
            if (rp >= p0 + cnp || rp + rc <= p0) continue;
            int base = s * SCHUNK + rsoff[s];
            for (int o = ql; o < rc; o += 16) {
                int g = rp + o;
                if (g >= p0 && g < p0 + cnp) sbufA[g - p0] = packed[base + o];
            }
        }
        if (t < 512) bins[t] = 0;
        __syncthreads();
        // hist: key = src_chunk*64 + ldst (448 used bins)
        for (int i = t; i < cnp; i += 1024) {
            unsigned e = sbufA[i];
            int key = (int)((((e & 0xffffu) >> CSH) << 6) | ((e >> 16) & 63u));
            atomicAdd(&bins[key], 1);
        }
        __syncthreads();
        {
            int v = (t < 512) ? bins[t] : 0;
            int si = v;
#pragma unroll
            for (int d = 1; d < 64; d <<= 1) {
                int u = __shfl_up(si, d);
                if (lane >= d) si += u;
            }
            if (t < 512 && lane == 63) wtot[w] = si;
            __syncthreads();
            if (t == 0) {
                int a2 = 0;
#pragma unroll
                for (int k = 0; k < 8; ++k) { int x = wtot[k]; wtot[k] = a2; a2 += x; }
            }
            __syncthreads();
            if (t < 512) {
                int excl = wtot[w] + si - v;
                cofs[t] = excl; ccur[t] = excl;
                if (t == 511) cofs[512] = excl + v;
            }
        }
        __syncthreads();
        for (int i = t; i < cnp; i += 1024) {
            unsigned e = sbufA[i];
            int key = (int)((((e & 0xffffu) >> CSH) << 6) | ((e >> 16) & 63u));
            int pos = atomicAdd(&ccur[key], 1);
            sbufB[pos] = (ushort)(e & 0xffffu);
        }
        __syncthreads();

        // gather: wave w owns nodes w*4..w*4+3; quarter-waves take alternate
        // edges; lane ql covers cols 8ql..8ql+7 via one uint4
        for (int c = 0; c < NCH; ++c) {
            const int kbase = c * 64 + w * 4;
#pragma unroll
            for (int i = 0; i < 4; ++i) {
                const int jb = cofs[kbase + i];
                const int je = cofs[kbase + i + 1];
                for (int j = jb + qw; j < je; j += 4) {
                    int sV = sbufB[j];
                    uint4 u = ((const uint4*)(hb + (size_t)sV * DD))[ql];
                    a[i][0] += lo16(u.x); a[i][1] += hi16(u.x);
                    a[i][2] += lo16(u.y); a[i][3] += hi16(u.y);
                    a[i][4] += lo16(u.z); a[i][5] += hi16(u.z);
                    a[i][6] += lo16(u.w); a[i][7] += hi16(u.w);
                }
            }
        }
        __syncthreads();
    }

    // cross-quarter-wave reduce: qw==0 lanes hold the full sums
#pragma unroll
    for (int i = 0; i < 4; ++i)
#pragma unroll
        for (int k = 0; k < 8; ++k) {
            a[i][k] += __shfl_down(a[i][k], 32);
            a[i][k] += __shfl_down(a[i][k], 16);
        }

    // ---- Phase B: GEMM1 on this block's 64-row tile (smem repurposed) ----
    ushort (*As)[136] = (ushort(*)[136])smem;             // 17408 B
    ushort (*Ws)[136] = (ushort(*)[136])(smem + 17408);   // 34816 B
    const int r0 = b << BSH;

    if (qw == 0) {
#pragma unroll
        for (int i = 0; i < 4; ++i) {
            int ulocal = w * 4 + i;
            int u = r0 + ulocal;
            uint4 st = make_uint4(0, 0, 0, 0);
            if (u < n) {
                uint4 hv = ((const uint4*)(hb + (size_t)u * DD))[ql];
                unsigned p0w = (unsigned)f2b(epsval * lo16(hv.x) + a[i][0])
                             | ((unsigned)f2b(epsval * hi16(hv.x) + a[i][1]) << 16);
                unsigned p1w = (unsigned)f2b(epsval * lo16(hv.y) + a[i][2])
                             | ((unsigned)f2b(epsval * hi16(hv.y) + a[i][3]) << 16);
                unsigned p2w = (unsigned)f2b(epsval * lo16(hv.z) + a[i][4])
                             | ((unsigned)f2b(epsval * hi16(hv.z) + a[i][5]) << 16);
                unsigned p3w = (unsigned)f2b(epsval * lo16(hv.w) + a[i][6])
                             | ((unsigned)f2b(epsval * hi16(hv.w) + a[i][7]) << 16);
                st = make_uint4(p0w, p1w, p2w, p3w);
            }
            *(uint4*)&As[ulocal][ql * 8] = st;
        }
    }
    // stage W1^T (pre-converted): 2048 uint4, 2 per thread
#pragma unroll
    for (int jj = 0; jj < 2; ++jj) {
        int f = jj * 1024 + t;
        int r = f >> 4, c8 = f & 15;
        *(uint4*)&Ws[r][c8 * 8] = ((const uint4*)wt)[f];
    }
    __syncthreads();

    // 16 waves x 2 col-tiles: wave w -> m=w&3, n = (w>>2)*2 + {0,1}
    const int m = w & 3;
    const int npair = w >> 2;
    short8 afr[4];
    const ushort* arow = &As[m * 16 + ql][0];
#pragma unroll
    for (int k = 0; k < 4; ++k)
        afr[k] = *(const short8*)(arow + k * 32 + qw * 8);
#pragma unroll
    for (int nn = 0; nn < 2; ++nn) {
        int nt = npair * 2 + nn;
        const ushort* brow = &Ws[nt * 16 + ql][0];
        float4v acc = (float4v)(0.f);
#pragma unroll
        for (int k = 0; k < 4; ++k) {
            short8 bfr = *(const short8*)(brow + k * 32 + qw * 8);
            acc = __builtin_amdgcn_mfma_f32_16x16x32_bf16(afr[k], bfr, acc, 0, 0, 0);
        }
        float bv = bias[nt * 16 + ql];
#pragma unroll
        for (int r = 0; r < 4; ++r) {
            int row = r0 + m * 16 + qw * 4 + r;
            if (row < n) {
                float o = fmaxf(acc[r] + bv, 0.f);
                z1b[(size_t)row * DD + nt * 16 + ql] = f2b(o);
            }
        }
    }
}

// ---------- K3: MFMA GEMM2 + BN stats ----------
__global__ __launch_bounds__(256) void mgemm2_kernel(
        const ushort* __restrict__ Ab, const ushort* __restrict__ wt,
        const float* __restrict__ bias, float* __restrict__ outf,
        float* __restrict__ stats, int n) {
    __shared__ ushort As[64][136];
    __shared__ ushort Ws[128][136];
    __shared__ float Ssum[128];
    __shared__ float Ssq[128];

    const int t = threadIdx.x;
    const int lane = t & 63;
    const int w = t >> 6;
    const int quad = lane >> 4;
    const int l16 = lane & 15;
    const int row0 = blockIdx.x * 64;

    if (t < 128) { Ssum[t] = 0.f; Ssq[t] = 0.f; }

#pragma unroll
    for (int jj = 0; jj < 8; ++jj) {
        int f = jj * 256 + t;
        int r = f >> 4, c8 = f & 15;
        *(uint4*)&Ws[r][c8 * 8] = ((const uint4*)wt)[f];
    }
#pragma unroll
    for (int jj = 0; jj < 4; ++jj) {
        int p = jj * 256 + t;
        int r = p >> 4;
        int c8 = p & 15;
        int row = row0 + r;
        uint4 v = make_uint4(0, 0, 0, 0);
        if (row < n)
            v = *((const uint4*)(Ab + (size_t)row * DD) + c8);
        *(uint4*)&As[r][c8 * 8] = v;
    }
    __syncthreads();

    short8 afr[4];
    const ushort* arow = &As[w * 16 + l16][0];
#pragma unroll
    for (int k = 0; k < 4; ++k)
        afr[k] = *(const short8*)(arow + k * 32 + quad * 8);

    float4v acc[8];
#pragma unroll
    for (int i = 0; i < 8; ++i) acc[i] = (float4v)(0.f);

#pragma unroll
    for (int nt = 0; nt < 8; ++nt) {
        const ushort* brow = &Ws[nt * 16 + l16][0];
#pragma unroll
        for (int k = 0; k < 4; ++k) {
            short8 bfr = *(const short8*)(brow + k * 32 + quad * 8);
            acc[nt] = __builtin_amdgcn_mfma_f32_16x16x32_bf16(afr[k], bfr, acc[nt], 0, 0, 0);
        }
    }

#pragma unroll
    for (int nt = 0; nt < 8; ++nt) {
        float bv = bias[nt * 16 + l16];
        float s = 0.f, q = 0.f;
#pragma unroll
        for (int r = 0; r < 4; ++r) {
            int row = row0 + w * 16 + quad * 4 + r;
            if (row < n) {
                float o = acc[nt][r] + bv;
                outf[(size_t)row * DD + nt * 16 + l16] = o;
                s += o;
                q += o * o;
            }
        }
        atomicAdd(&Ssum[nt * 16 + l16], s);
        atomicAdd(&Ssq[nt * 16 + l16], q);
    }
    __syncthreads();
    if (t < 128) {
        atomicAdd(&stats[t], Ssum[t]);
        atomicAdd(&stats[128 + t], Ssq[t]);
    }
}

// ---------- K4: BN finalize (in-block) + leaky relu + residual ----------
__global__ __launch_bounds__(256) void applybn_kernel(
        const float* __restrict__ h, const float* __restrict__ z2,
        const float* __restrict__ stats, const float* __restrict__ gamma,
        const float* __restrict__ beta, float* __restrict__ out,
        int n, int total4) {
    __shared__ float sc[128];
    __shared__ float sh[128];
    const int t = threadIdx.x;
    if (t < 128) {
        float inv_n = 1.0f / (float)n;
        float mean = stats[t] * inv_n;
        float var = stats[128 + t] * inv_n - mean * mean;
        float s = gamma[t] * rsqrtf(var + BN_EPS);
        sc[t] = s;
        sh[t] = beta[t] - mean * s;
    }
    __syncthreads();
    for (int i = blockIdx.x * 256 + t; i < total4; i += gridDim.x * 256) {
        int c4 = i & 31;
        float4 scv = ((const float4*)sc)[c4];
        float4 shv = ((const float4*)sh)[c4];
        float4 z = ((const float4*)z2)[i];
        float4 hh = ((const float4*)h)[i];
        float4 o;
        float v;
        v = fmaf(z.x, scv.x, shv.x); o.x = hh.x + (v >= 0.f ? v : SLOPE * v);
        v = fmaf(z.y, scv.y, shv.y); o.y = hh.y + (v >= 0.f ? v : SLOPE * v);
        v = fmaf(z.z, scv.z, shv.z); o.z = hh.z + (v >= 0.f ? v : SLOPE * v);
        v = fmaf(z.w, scv.w, shv.w); o.w = hh.w + (v >= 0.f ? v : SLOPE * v);
        ((float4*)out)[i] = o;
    }
}

extern "C" void kernel_launch(void* const* d_in, const int* in_sizes, int n_in,
                              void* d_out, int out_size, void* d_ws, size_t ws_size,
                              hipStream_t stream) {
    const float* h     = (const float*)d_in[0];
    const int*   src   = (const int*)d_in[1];
    const int*   dst   = (const int*)d_in[2];
    const float* eps   = (const float*)d_in[3];
    const float* W1    = (const float*)d_in[4];
    const float* b1    = (const float*)d_in[5];
    const float* W2    = (const float*)d_in[6];
    const float* b2    = (const float*)d_in[7];
    const float* gamma = (const float*)d_in[8];
    const float* beta  = (const float*)d_in[9];
    float* out = (float*)d_out;

    const int n = in_sizes[0] / DD;   // 50000
    const int E = in_sizes[1];        // 1600000
    const int NB = (n + BROWS - 1) / BROWS;    // 782
    const int NS = (E + SCHUNK - 1) / SCHUNK;  // 196
    const int total4 = n * DD / 4;

    // workspace layout: z1b | z2 | hb | packed | cnt | lofs | stats | wt1 | wt2
    ushort* z1b      = (ushort*)d_ws;
    float* z2        = (float*)(z1b + (size_t)n * DD);
    ushort* hb       = (ushort*)(z2 + (size_t)n * DD);
    unsigned* packed = (unsigned*)(hb + (size_t)n * DD);
    int* cnt         = (int*)(packed + (size_t)NS * SCHUNK);
    int* lofs        = cnt + (size_t)NS * NB;
    float* stats     = (float*)(lofs + (size_t)NS * NB);
    ushort* wt1      = (ushort*)(stats + 256);
    ushort* wt2      = wt1 + DD * DD;

    hipMemsetAsync(stats, 0, 256 * sizeof(float), stream);

    // K1: fused prep + chunk sort
    scatb5_kernel<<<NS, 1024, 0, stream>>>(h, hb, W1, W2, wt1, wt2, src, dst,
                                           cnt, lofs, packed, total4, E, NB);
    // K2: fused gather + GEMM1 -> z1b (agg never materialized)
    aggemm_kernel<<<NB, 1024, 0, stream>>>(hb, cnt, lofs, packed, eps, wt1, b1,
                                           z1b, n, NB, NS);
    // K3: GEMM2 + BN stats -> z2
    mgemm2_kernel<<<(n + 63) / 64, 256, 0, stream>>>(z1b, wt2, b2, z2, stats, n);
    // K4: BN finalize + leaky relu + residual -> out
    applybn_kernel<<<1024, 256, 0, stream>>>(h, z2, stats, gamma, beta, out,
                                             n, total4);
}